// Round 9
// baseline (564.022 us; speedup 1.0000x reference)
//
#include <hip/hip_runtime.h>
#include <hip/hip_bf16.h>
#include <math.h>

// ---------------------------------------------------------------------------
// GCN part-seg pipeline.
// R9: BN=256 8-wave tiles for GCN1/GCN2 (halve A re-reads); z stored fp16
//     (MODE 4) halving GCN3 write + final gather; generalized WAVES template.
//     Rest identical to R8 (4-plane staging, fp16 gather tables, fused ends).
// ---------------------------------------------------------------------------

typedef __attribute__((ext_vector_type(8))) short short8;     // 8 bf16
typedef __attribute__((ext_vector_type(8))) _Float16 half8;   // 8 fp16
typedef __attribute__((ext_vector_type(4))) float floatx4;    // 4 fp32

__device__ __forceinline__ unsigned short bf16h(float f) {
    unsigned int u = __float_as_uint(f);
    u += 0x7fff + ((u >> 16) & 1);          // round-to-nearest-even
    return (unsigned short)(u >> 16);
}
__device__ __forceinline__ float bf16f(unsigned short h) {
    return __uint_as_float(((unsigned int)h) << 16);
}

__device__ __forceinline__ void gld_lds16(unsigned short* lds, const unsigned short* g) {
    __builtin_amdgcn_global_load_lds(
        (const __attribute__((address_space(1))) unsigned int*)g,
        (__attribute__((address_space(3))) unsigned int*)lds, 16, 0, 0);
}

// ---------------- degree / CSR build ----------------

__global__ void hist_kernel(const int* __restrict__ dst, int* __restrict__ counts, int e) {
    int g = blockIdx.x * blockDim.x + threadIdx.x;
    if (g < e) atomicAdd(&counts[dst[g]], 1);
}

__global__ void scan1_kernel(const int* __restrict__ counts, int* __restrict__ bsum, int n) {
    __shared__ int buf[256];
    int i = blockIdx.x * 256 + threadIdx.x;
    buf[threadIdx.x] = (i < n) ? counts[i] : 0;
    __syncthreads();
    for (int off = 128; off > 0; off >>= 1) {
        if (threadIdx.x < off) buf[threadIdx.x] += buf[threadIdx.x + off];
        __syncthreads();
    }
    if (threadIdx.x == 0) bsum[blockIdx.x] = buf[0];
}

__global__ void scan2_kernel(const int* __restrict__ bsum, int* __restrict__ bsumx,
                             int* __restrict__ offsets, int nb, int n) {
    __shared__ int buf[256];
    int tid = threadIdx.x;
    int v = (tid < nb) ? bsum[tid] : 0;
    buf[tid] = v;
    __syncthreads();
    for (int off = 1; off < 256; off <<= 1) {
        int t = (tid >= off) ? buf[tid - off] : 0;
        __syncthreads();
        buf[tid] += t;
        __syncthreads();
    }
    if (tid < nb) bsumx[tid] = buf[tid] - v;       // exclusive
    if (tid == 255) offsets[n] = buf[255];          // total
}

__global__ void scan3_kernel(const int* __restrict__ counts, const int* __restrict__ bsumx,
                             int* __restrict__ offsets, int* __restrict__ cursor,
                             float* __restrict__ dinv, int n) {
    __shared__ int buf[256];
    int tid = threadIdx.x;
    int i = blockIdx.x * 256 + tid;
    int c = (i < n) ? counts[i] : 0;
    buf[tid] = c;
    __syncthreads();
    for (int off = 1; off < 256; off <<= 1) {
        int t = (tid >= off) ? buf[tid - off] : 0;
        __syncthreads();
        buf[tid] += t;
        __syncthreads();
    }
    if (i < n) {
        int excl = bsumx[blockIdx.x] + buf[tid] - c;
        offsets[i] = excl;
        cursor[i] = excl;
        dinv[i] = rsqrtf((float)c + 1.0f);
    }
}

__global__ void fill_kernel(const int* __restrict__ src, const int* __restrict__ dst,
                            const float* __restrict__ dinv, int* __restrict__ cursor,
                            int* __restrict__ ssrc, float* __restrict__ snorm, int e) {
    int g = blockIdx.x * blockDim.x + threadIdx.x;
    if (g >= e) return;
    int s = src[g], d = dst[g];
    int pos = atomicAdd(&cursor[d], 1);
    ssrc[pos]  = s;
    snorm[pos] = dinv[s] * dinv[d];
}

// ---------------- fused weight prep: W[K][N] fp32 -> Bt[N][2K] = [Bh;Bl] ----

__device__ __forceinline__ void wsplit_one(float w, unsigned short* Bt, int k, int n, int K) {
    unsigned short h = bf16h(w);
    unsigned short l = bf16h(w - bf16f(h));
    size_t base = (size_t)n * (2 * K);
    Bt[base + k]     = h;
    Bt[base + K + k] = l;
}

__global__ void prepw_kernel(const float* __restrict__ g1w, const float* __restrict__ g2w,
                             const float* __restrict__ g3w, const float* __restrict__ w3,
                             unsigned short* __restrict__ Bt1,
                             unsigned short* __restrict__ Bt2,
                             unsigned short* __restrict__ Bt3,
                             unsigned short* __restrict__ Bt0) {
    int gid = blockIdx.x * blockDim.x + threadIdx.x;
    if (gid < 32768) {                       // g1: K=128, N=256
        int k = gid >> 8, n = gid & 255;
        wsplit_one(g1w[gid], Bt1, k, n, 128);
    } else if (gid < 32768 + 131072) {       // g2: K=256, N=512
        int idx = gid - 32768;
        int k = idx >> 9, n = idx & 511;
        wsplit_one(g2w[idx], Bt2, k, n, 256);
    } else if (gid < 32768 + 131072 + 32768) { // g3 padded: K=512, N=64
        int idx = gid - 32768 - 131072;
        int k = idx >> 6, c = idx & 63;
        float w = (c < 50) ? g3w[k * 50 + c] : 0.0f;
        wsplit_one(w, Bt3, k, c, 512);
    } else if (gid < 32768 + 131072 + 32768 + 8192) { // w3: K=64, N=128
        int idx = gid - 32768 - 131072 - 32768;
        int k = idx >> 7, n = idx & 127;
        wsplit_one(w3[idx], Bt0, k, n, 64);
    }
}

// ---------------- fused MLP layers 1+2: x[N,3] -> h2 hi/lo bf16 planes ------

__global__ __launch_bounds__(256) void mlp12_kernel(
        const float* __restrict__ x,
        const float* __restrict__ w1, const float* __restrict__ b1,
        const float* __restrict__ w2, const float* __restrict__ b2,
        unsigned short* __restrict__ H2h, unsigned short* __restrict__ H2l, int n) {
    __shared__ float sw1[96], sb1[32], sw2[2048], sb2[64];
    int tid = threadIdx.x;
    if (tid < 96) sw1[tid] = w1[tid];
    if (tid < 32) sb1[tid] = b1[tid];
    if (tid < 64) sb2[tid] = b2[tid];
    for (int i = tid; i < 2048; i += 256) sw2[i] = w2[i];
    __syncthreads();

    int node = blockIdx.x * 256 + tid;
    if (node >= n) return;
    float x0 = x[node * 3 + 0], x1 = x[node * 3 + 1], x2 = x[node * 3 + 2];
    float h1[32];
#pragma unroll
    for (int j = 0; j < 32; j++)
        h1[j] = fmaxf(sb1[j] + x0 * sw1[j] + x1 * sw1[32 + j] + x2 * sw1[64 + j], 0.0f);

    float acc[64];
#pragma unroll
    for (int j = 0; j < 64; j++) acc[j] = sb2[j];
    for (int k = 0; k < 32; k++) {
        float hk = h1[k];
#pragma unroll
        for (int j4 = 0; j4 < 16; j4++) {
            float4 w = *(const float4*)&sw2[k * 64 + j4 * 4];
            acc[j4 * 4 + 0] = fmaf(hk, w.x, acc[j4 * 4 + 0]);
            acc[j4 * 4 + 1] = fmaf(hk, w.y, acc[j4 * 4 + 1]);
            acc[j4 * 4 + 2] = fmaf(hk, w.z, acc[j4 * 4 + 2]);
            acc[j4 * 4 + 3] = fmaf(hk, w.w, acc[j4 * 4 + 3]);
        }
    }
#pragma unroll
    for (int j4 = 0; j4 < 16; j4++) {
        ushort4 h4, l4;
        unsigned short* hp = (unsigned short*)&h4;
        unsigned short* lp = (unsigned short*)&l4;
#pragma unroll
        for (int t = 0; t < 4; t++) {
            float v = fmaxf(acc[j4 * 4 + t], 0.0f);
            unsigned short h = bf16h(v);
            hp[t] = h;
            lp[t] = bf16h(v - bf16f(h));
        }
        *(ushort4*)&H2h[(size_t)node * 64 + j4 * 4] = h4;
        *(ushort4*)&H2l[(size_t)node * 64 + j4 * 4] = l4;
    }
}

// ---------------- MFMA GEMM, double-bf16, 4-plane staging, WAVES waves ------
// C[M,N] = (Ah+Al)[M,K] @ (Bh+Bl)[K,N]  ~=  AhBh + AhBl + AlBh.
// Bt[N][2K] = [Bh;Bl]. BM=128, BK=32. Block = WAVES*64 threads.
// MODE 0: Cf=relu(C+bias). MODE 1: relu(C+bias) -> Ch/Cl bf16 planes.
// MODE 2: Cf=C. MODE 3: fp16(relu(C+bias)) -> Ch. MODE 4: fp16(C) -> Ch.

template<int BN, int WAVES, int WGR, int WGC, int WRF, int WCF, int MODE>
__global__ __launch_bounds__(WAVES * 64) void gemm_mfma_kernel(
        const unsigned short* __restrict__ Ah, const unsigned short* __restrict__ Al,
        const unsigned short* __restrict__ Bt, const float* __restrict__ bias,
        float* __restrict__ Cf, unsigned short* __restrict__ Ch,
        unsigned short* __restrict__ Cl, int M, int K, int N) {
    static_assert(WGR * WRF * 16 == 128, "row cover");
    static_assert(WGC * WCF * 16 == BN, "col cover");
    static_assert(WGR * WGC == WAVES, "wave grid");
    static_assert(16 % WAVES == 0 || WAVES % 16 == 0, "");
    __shared__ __align__(16) unsigned short Ash[128 * 32];
    __shared__ __align__(16) unsigned short Asl[128 * 32];
    __shared__ __align__(16) unsigned short Bsh[BN * 32];
    __shared__ __align__(16) unsigned short Bsl[BN * 32];

    const int tid  = threadIdx.x;
    const int lane = tid & 63;
    const int wave = tid >> 6;
    const int bm = blockIdx.y * 128;
    const int bn = blockIdx.x * BN;
    const int K2 = 2 * K;

    const int wr0 = (wave / WGC) * (WRF * 16);
    const int wc0 = (wave % WGC) * (WCF * 16);
    const int lr   = lane & 15;
    const int quad = lane >> 4;
    const int arow = lane >> 2;          // row within 16-row group
    const int acol = (lane & 3) * 8;     // halves within 32-half row

    floatx4 acc[WRF][WCF];
#pragma unroll
    for (int i = 0; i < WRF; i++)
#pragma unroll
        for (int j = 0; j < WCF; j++) acc[i][j] = floatx4{0.f, 0.f, 0.f, 0.f};

    for (int k0 = 0; k0 < K; k0 += 32) {
        // A: 8 row-groups x 2 planes = 16 wave-units
#pragma unroll
        for (int u = 0; u < 16 / WAVES; u++) {
            int unit = wave + u * WAVES;
            int grp = unit >> 1, pl = unit & 1;
            int gm = bm + grp * 16 + arow;
            if (gm >= M) gm = M - 1;     // clamp: garbage rows discarded at store
            size_t go = (size_t)gm * K + k0 + acol;
            if (pl) gld_lds16(&Asl[grp * 512], Al + go);
            else    gld_lds16(&Ash[grp * 512], Ah + go);
        }
        // B: BN/16 col-groups x 2 planes = BN/8 wave-units
#pragma unroll
        for (int u = 0; u < (BN / 8) / WAVES; u++) {
            int unit = wave + u * WAVES;
            int grp = unit >> 1, pl = unit & 1;
            int gr = bn + grp * 16 + arow;
            size_t go = (size_t)gr * K2 + k0 + acol + (pl ? K : 0);
            if (pl) gld_lds16(&Bsl[grp * 512], Bt + go);
            else    gld_lds16(&Bsh[grp * 512], Bt + go);
        }
        __syncthreads();

        short8 ahf[WRF], alf[WRF], bhf[WCF], blf[WCF];
#pragma unroll
        for (int i = 0; i < WRF; i++) {
            int ro = (wr0 + i * 16 + lr) * 32 + quad * 8;
            ahf[i] = *reinterpret_cast<const short8*>(&Ash[ro]);
            alf[i] = *reinterpret_cast<const short8*>(&Asl[ro]);
        }
#pragma unroll
        for (int j = 0; j < WCF; j++) {
            int ro = (wc0 + j * 16 + lr) * 32 + quad * 8;
            bhf[j] = *reinterpret_cast<const short8*>(&Bsh[ro]);
            blf[j] = *reinterpret_cast<const short8*>(&Bsl[ro]);
        }
#pragma unroll
        for (int i = 0; i < WRF; i++)
#pragma unroll
            for (int j = 0; j < WCF; j++) {
                acc[i][j] = __builtin_amdgcn_mfma_f32_16x16x32_bf16(
                    ahf[i], bhf[j], acc[i][j], 0, 0, 0);
                acc[i][j] = __builtin_amdgcn_mfma_f32_16x16x32_bf16(
                    ahf[i], blf[j], acc[i][j], 0, 0, 0);
                acc[i][j] = __builtin_amdgcn_mfma_f32_16x16x32_bf16(
                    alf[i], bhf[j], acc[i][j], 0, 0, 0);
            }
        __syncthreads();
    }

    // epilogue: C/D layout col=lane&15, row=quad*4+reg (m89-verified)
#pragma unroll
    for (int i = 0; i < WRF; i++) {
#pragma unroll
        for (int j = 0; j < WCF; j++) {
            int gc = bn + wc0 + j * 16 + lr;
#pragma unroll
            for (int reg = 0; reg < 4; reg++) {
                int gr = bm + wr0 + i * 16 + quad * 4 + reg;
                if (gr >= M) continue;
                float v = acc[i][j][reg];
                if (MODE == 0) {
                    v = fmaxf(v + bias[gc], 0.0f);
                    Cf[(size_t)gr * N + gc] = v;
                } else if (MODE == 1) {
                    v = fmaxf(v + bias[gc], 0.0f);
                    unsigned short h = bf16h(v);
                    unsigned short l = bf16h(v - bf16f(h));
                    Ch[(size_t)gr * N + gc] = h;
                    Cl[(size_t)gr * N + gc] = l;
                } else if (MODE == 2) {
                    Cf[(size_t)gr * N + gc] = v;
                } else if (MODE == 3) {  // fp16 activation store
                    v = fmaxf(v + bias[gc], 0.0f);
                    ((_Float16*)Ch)[(size_t)gr * N + gc] = (_Float16)v;
                } else {                 // MODE 4: fp16 raw store
                    ((_Float16*)Ch)[(size_t)gr * N + gc] = (_Float16)v;
                }
            }
        }
    }
}

// ---------------- aggregation from fp16 table: thread per (node, half8) -----

template<int F>
__global__ void agg_f16_kernel(const _Float16* __restrict__ table,
                               const int* __restrict__ offsets,
                               const int* __restrict__ ssrc,
                               const float* __restrict__ snorm,
                               const float* __restrict__ dinv,
                               unsigned short* __restrict__ Ah,
                               unsigned short* __restrict__ Al, int n) {
    constexpr int F8 = F / 8;
    int gid = blockIdx.x * blockDim.x + threadIdx.x;
    if (gid >= n * F8) return;
    int node = gid / F8;                 // F8 pow2 -> shift
    int c8 = (gid - node * F8) * 8;

    float acc[8];
#pragma unroll
    for (int i = 0; i < 8; i++) acc[i] = 0.0f;

    int beg = offsets[node], end = offsets[node + 1];
    for (int e = beg; e < end; ++e) {
        int s = ssrc[e];
        float w = snorm[e];
        half8 r = *reinterpret_cast<const half8*>(table + (size_t)s * F + c8);
#pragma unroll
        for (int i = 0; i < 8; i++) acc[i] = fmaf((float)r[i], w, acc[i]);
    }
    float dv = dinv[node];
    float sw = dv * dv;
    half8 r = *reinterpret_cast<const half8*>(table + (size_t)node * F + c8);
#pragma unroll
    for (int i = 0; i < 8; i++) acc[i] = fmaf((float)r[i], sw, acc[i]);

    unsigned short hb[8], lb[8];
#pragma unroll
    for (int i = 0; i < 8; i++) {
        unsigned short h = bf16h(acc[i]);
        hb[i] = h;
        lb[i] = bf16h(acc[i] - bf16f(h));
    }
    *(uint4*)&Ah[(size_t)node * F + c8] = *(uint4*)hb;
    *(uint4*)&Al[(size_t)node * F + c8] = *(uint4*)lb;
}

// ---------------- fused final aggregation + softmax: one wave per node ------
// z[N,64] fp16 (cols 50..63 zero); out[N,50] = softmax(AGG(z)+bias).

__global__ void agg50_softmax_kernel(const _Float16* __restrict__ z,
                                     const int* __restrict__ offsets,
                                     const int* __restrict__ ssrc,
                                     const float* __restrict__ snorm,
                                     const float* __restrict__ dinv,
                                     const float* __restrict__ bias,
                                     float* __restrict__ out, int n) {
    int node = blockIdx.x * 4 + (threadIdx.x >> 6);
    int lane = threadIdx.x & 63;
    if (node >= n) return;

    float a = 0.0f;
    int beg = offsets[node], end = offsets[node + 1];
    for (int e = beg; e < end; ++e) {
        int s = ssrc[e];
        a = fmaf((float)z[(size_t)s * 64 + lane], snorm[e], a);
    }
    float dv = dinv[node];
    a = fmaf((float)z[(size_t)node * 64 + lane], dv * dv, a);

    float v = (lane < 50) ? a + bias[lane] : -INFINITY;
    float m = v;
#pragma unroll
    for (int off = 32; off > 0; off >>= 1) m = fmaxf(m, __shfl_xor(m, off));
    float e = (lane < 50) ? expf(v - m) : 0.0f;
    float s = e;
#pragma unroll
    for (int off = 32; off > 0; off >>= 1) s += __shfl_xor(s, off);
    if (lane < 50) out[(size_t)node * 50 + lane] = e / s;
}

// ---------------------------------------------------------------------------

extern "C" void kernel_launch(void* const* d_in, const int* in_sizes, int n_in,
                              void* d_out, int out_size, void* d_ws, size_t ws_size,
                              hipStream_t stream) {
    const float* x    = (const float*)d_in[0];
    const int*   ei   = (const int*)  d_in[1];
    const float* w1   = (const float*)d_in[2];
    const float* b1   = (const float*)d_in[3];
    const float* w2   = (const float*)d_in[4];
    const float* b2   = (const float*)d_in[5];
    const float* w3   = (const float*)d_in[6];
    const float* b3   = (const float*)d_in[7];
    const float* g1w  = (const float*)d_in[8];
    const float* g1b  = (const float*)d_in[9];
    const float* g2w  = (const float*)d_in[10];
    const float* g2b  = (const float*)d_in[11];
    const float* g3w  = (const float*)d_in[12];
    const float* g3b  = (const float*)d_in[13];
    float* out = (float*)d_out;

    const int N = in_sizes[0] / 3;      // 50000
    const int E = in_sizes[1] / 2;      // 800000
    const int* src = ei;
    const int* dst = ei + E;
    const int NB = (N + 255) / 256;     // 196

    // ---- workspace arena with liveness-based region reuse ----
    char* ws = (char*)d_ws;
    size_t off = 0;
    auto alloc = [&](size_t bytes) -> char* {
        char* p = ws + off;
        off = (off + bytes + 255) & ~(size_t)255;
        return p;
    };
    int*   counts  = (int*)  alloc((size_t)N * 4);
    int*   offsets = (int*)  alloc((size_t)(N + 1) * 4);
    int*   cursor  = (int*)  alloc((size_t)N * 4);
    float* dinv    = (float*)alloc((size_t)N * 4);
    int*   bsum    = (int*)  alloc((size_t)256 * 4);
    int*   bsumx   = (int*)  alloc((size_t)256 * 4);
    int*   ssrc    = (int*)  alloc((size_t)E * 4);
    float* snorm   = (float*)alloc((size_t)E * 4);
    unsigned short* Bt1 = (unsigned short*)alloc((size_t)256 * 256 * 2);
    unsigned short* Bt2 = (unsigned short*)alloc((size_t)512 * 512 * 2);
    unsigned short* Bt3 = (unsigned short*)alloc((size_t)64 * 1024 * 2);
    unsigned short* Bt0 = (unsigned short*)alloc((size_t)128 * 128 * 2);
    char* R1 = alloc((size_t)N * 256 * 4);   // 51.2 MB
    char* R2 = alloc((size_t)N * 256 * 4);   // 51.2 MB
    char* R3 = alloc((size_t)N * 512 * 4);   // 102.4 MB
    (void)ws_size;

    // R1 phase 1: S128f16 [N,128] fp16 | A128h | A128l   phase 2: A256h|A256l
    _Float16*       S128f = (_Float16*)R1;
    unsigned short* A128h = (unsigned short*)(R1 + (size_t)N * 128 * 2);
    unsigned short* A128l = (unsigned short*)(R1 + (size_t)N * 128 * 4);
    unsigned short* A256h = (unsigned short*)R1;
    unsigned short* A256l = (unsigned short*)(R1 + (size_t)N * 256 * 2);
    // R2 phase 1: H2h|H2l [N,64] bf16   phase 2: G1f16 [N,256] fp16
    // phase 3: zbuf [N,64] fp16
    unsigned short* H2h  = (unsigned short*)R2;
    unsigned short* H2l  = (unsigned short*)(R2 + (size_t)N * 64 * 2);
    _Float16*       G1f  = (_Float16*)R2;
    _Float16*       zbuf = (_Float16*)R2;
    // R3: A512h | A512l
    unsigned short* A512h = (unsigned short*)R3;
    unsigned short* A512l = (unsigned short*)(R3 + (size_t)N * 512 * 2);

    // ---- degree + CSR + weight prep ----
    hipMemsetAsync(counts, 0, (size_t)N * 4, stream);
    hist_kernel<<<(E + 255) / 256, 256, 0, stream>>>(dst, counts, E);
    scan1_kernel<<<NB, 256, 0, stream>>>(counts, bsum, N);
    scan2_kernel<<<1, 256, 0, stream>>>(bsum, bsumx, offsets, NB, N);
    scan3_kernel<<<NB, 256, 0, stream>>>(counts, bsumx, offsets, cursor, dinv, N);
    fill_kernel<<<(E + 255) / 256, 256, 0, stream>>>(src, dst, dinv, cursor, ssrc, snorm, E);
    prepw_kernel<<<(204800 + 255) / 256, 256, 0, stream>>>(
        g1w, g2w, g3w, w3, Bt1, Bt2, Bt3, Bt0);

    const int MB = (N + 127) / 128;     // 391 row-blocks

    // ---- MLP: x -> h2 hi/lo (fused), h2 -> h3 fp16 table (MFMA, K=64) ----
    mlp12_kernel<<<NB, 256, 0, stream>>>(x, w1, b1, w2, b2, H2h, H2l, N);
    {   dim3 grid(1, MB);
        gemm_mfma_kernel<128, 4, 2, 2, 4, 4, 3><<<grid, 256, 0, stream>>>(
            H2h, H2l, Bt0, b3, nullptr, (unsigned short*)S128f, nullptr, N, 64, 128);
    }

    // ---- GCN1: agg@128 (fp16 table) -> MFMA 128->256 BN=256 (fp16 out) ----
    agg_f16_kernel<128><<<((size_t)N * 16 + 255) / 256, 256, 0, stream>>>(
        S128f, offsets, ssrc, snorm, dinv, A128h, A128l, N);
    {   dim3 grid(1, MB);
        gemm_mfma_kernel<256, 8, 2, 4, 4, 4, 3><<<grid, 512, 0, stream>>>(
            A128h, A128l, Bt1, g1b, nullptr, (unsigned short*)G1f, nullptr, N, 128, 256);
    }

    // ---- GCN2: agg@256 (fp16 table) -> MFMA 256->512 BN=256 (hi/lo out) ----
    agg_f16_kernel<256><<<((size_t)N * 32 + 255) / 256, 256, 0, stream>>>(
        G1f, offsets, ssrc, snorm, dinv, A256h, A256l, N);
    {   dim3 grid(2, MB);
        gemm_mfma_kernel<256, 8, 2, 4, 4, 4, 1><<<grid, 512, 0, stream>>>(
            A256h, A256l, Bt2, g2b, nullptr, A512h, A512l, N, 256, 512);
    }

    // ---- GCN3: MFMA 512->64 (fp16 out) -> fused agg@64 + softmax ----
    {   dim3 grid(1, MB);
        gemm_mfma_kernel<64, 4, 4, 1, 2, 4, 4><<<grid, 256, 0, stream>>>(
            A512h, A512l, Bt3, nullptr, nullptr, (unsigned short*)zbuf, nullptr, N, 512, 64);
    }
    agg50_softmax_kernel<<<(N + 3) / 4, 256, 0, stream>>>(
        zbuf, offsets, ssrc, snorm, dinv, g3b, out, N);
}

// Round 10
// 518.308 us; speedup vs baseline: 1.0882x; 1.0882x over previous
//
#include <hip/hip_runtime.h>
#include <hip/hip_bf16.h>
#include <math.h>

// ---------------------------------------------------------------------------
// GCN part-seg pipeline.
// R10: revert GEMMs to R8 geometry (BN=128/4-wave; R9's BN=256 starved
//      inter-block overlap). GCN2 epilogue -> single fp16 plane (halves A512
//      write); GCN3 GEMM gains AF16 path (in-register hi/lo split of fp16 A)
//      + BM=64 tiles (782 blocks, was 391). Rest as R8.
// ---------------------------------------------------------------------------

typedef __attribute__((ext_vector_type(8))) short short8;     // 8 bf16
typedef __attribute__((ext_vector_type(8))) _Float16 half8;   // 8 fp16
typedef __attribute__((ext_vector_type(4))) float floatx4;    // 4 fp32

__device__ __forceinline__ unsigned short bf16h(float f) {
    unsigned int u = __float_as_uint(f);
    u += 0x7fff + ((u >> 16) & 1);          // round-to-nearest-even
    return (unsigned short)(u >> 16);
}
__device__ __forceinline__ float bf16f(unsigned short h) {
    return __uint_as_float(((unsigned int)h) << 16);
}

__device__ __forceinline__ void gld_lds16(unsigned short* lds, const unsigned short* g) {
    __builtin_amdgcn_global_load_lds(
        (const __attribute__((address_space(1))) unsigned int*)g,
        (__attribute__((address_space(3))) unsigned int*)lds, 16, 0, 0);
}

// ---------------- degree / CSR build ----------------

__global__ void hist_kernel(const int* __restrict__ dst, int* __restrict__ counts, int e) {
    int g = blockIdx.x * blockDim.x + threadIdx.x;
    if (g < e) atomicAdd(&counts[dst[g]], 1);
}

__global__ void scan1_kernel(const int* __restrict__ counts, int* __restrict__ bsum, int n) {
    __shared__ int buf[256];
    int i = blockIdx.x * 256 + threadIdx.x;
    buf[threadIdx.x] = (i < n) ? counts[i] : 0;
    __syncthreads();
    for (int off = 128; off > 0; off >>= 1) {
        if (threadIdx.x < off) buf[threadIdx.x] += buf[threadIdx.x + off];
        __syncthreads();
    }
    if (threadIdx.x == 0) bsum[blockIdx.x] = buf[0];
}

__global__ void scan2_kernel(const int* __restrict__ bsum, int* __restrict__ bsumx,
                             int* __restrict__ offsets, int nb, int n) {
    __shared__ int buf[256];
    int tid = threadIdx.x;
    int v = (tid < nb) ? bsum[tid] : 0;
    buf[tid] = v;
    __syncthreads();
    for (int off = 1; off < 256; off <<= 1) {
        int t = (tid >= off) ? buf[tid - off] : 0;
        __syncthreads();
        buf[tid] += t;
        __syncthreads();
    }
    if (tid < nb) bsumx[tid] = buf[tid] - v;       // exclusive
    if (tid == 255) offsets[n] = buf[255];          // total
}

__global__ void scan3_kernel(const int* __restrict__ counts, const int* __restrict__ bsumx,
                             int* __restrict__ offsets, int* __restrict__ cursor,
                             float* __restrict__ dinv, int n) {
    __shared__ int buf[256];
    int tid = threadIdx.x;
    int i = blockIdx.x * 256 + tid;
    int c = (i < n) ? counts[i] : 0;
    buf[tid] = c;
    __syncthreads();
    for (int off = 1; off < 256; off <<= 1) {
        int t = (tid >= off) ? buf[tid - off] : 0;
        __syncthreads();
        buf[tid] += t;
        __syncthreads();
    }
    if (i < n) {
        int excl = bsumx[blockIdx.x] + buf[tid] - c;
        offsets[i] = excl;
        cursor[i] = excl;
        dinv[i] = rsqrtf((float)c + 1.0f);
    }
}

__global__ void fill_kernel(const int* __restrict__ src, const int* __restrict__ dst,
                            const float* __restrict__ dinv, int* __restrict__ cursor,
                            int* __restrict__ ssrc, float* __restrict__ snorm, int e) {
    int g = blockIdx.x * blockDim.x + threadIdx.x;
    if (g >= e) return;
    int s = src[g], d = dst[g];
    int pos = atomicAdd(&cursor[d], 1);
    ssrc[pos]  = s;
    snorm[pos] = dinv[s] * dinv[d];
}

// ---------------- fused weight prep: W[K][N] fp32 -> Bt[N][2K] = [Bh;Bl] ----

__device__ __forceinline__ void wsplit_one(float w, unsigned short* Bt, int k, int n, int K) {
    unsigned short h = bf16h(w);
    unsigned short l = bf16h(w - bf16f(h));
    size_t base = (size_t)n * (2 * K);
    Bt[base + k]     = h;
    Bt[base + K + k] = l;
}

__global__ void prepw_kernel(const float* __restrict__ g1w, const float* __restrict__ g2w,
                             const float* __restrict__ g3w, const float* __restrict__ w3,
                             unsigned short* __restrict__ Bt1,
                             unsigned short* __restrict__ Bt2,
                             unsigned short* __restrict__ Bt3,
                             unsigned short* __restrict__ Bt0) {
    int gid = blockIdx.x * blockDim.x + threadIdx.x;
    if (gid < 32768) {                       // g1: K=128, N=256
        int k = gid >> 8, n = gid & 255;
        wsplit_one(g1w[gid], Bt1, k, n, 128);
    } else if (gid < 32768 + 131072) {       // g2: K=256, N=512
        int idx = gid - 32768;
        int k = idx >> 9, n = idx & 511;
        wsplit_one(g2w[idx], Bt2, k, n, 256);
    } else if (gid < 32768 + 131072 + 32768) { // g3 padded: K=512, N=64
        int idx = gid - 32768 - 131072;
        int k = idx >> 6, c = idx & 63;
        float w = (c < 50) ? g3w[k * 50 + c] : 0.0f;
        wsplit_one(w, Bt3, k, c, 512);
    } else if (gid < 32768 + 131072 + 32768 + 8192) { // w3: K=64, N=128
        int idx = gid - 32768 - 131072 - 32768;
        int k = idx >> 7, n = idx & 127;
        wsplit_one(w3[idx], Bt0, k, n, 64);
    }
}

// ---------------- fused MLP layers 1+2: x[N,3] -> h2 hi/lo bf16 planes ------

__global__ __launch_bounds__(256) void mlp12_kernel(
        const float* __restrict__ x,
        const float* __restrict__ w1, const float* __restrict__ b1,
        const float* __restrict__ w2, const float* __restrict__ b2,
        unsigned short* __restrict__ H2h, unsigned short* __restrict__ H2l, int n) {
    __shared__ float sw1[96], sb1[32], sw2[2048], sb2[64];
    int tid = threadIdx.x;
    if (tid < 96) sw1[tid] = w1[tid];
    if (tid < 32) sb1[tid] = b1[tid];
    if (tid < 64) sb2[tid] = b2[tid];
    for (int i = tid; i < 2048; i += 256) sw2[i] = w2[i];
    __syncthreads();

    int node = blockIdx.x * 256 + tid;
    if (node >= n) return;
    float x0 = x[node * 3 + 0], x1 = x[node * 3 + 1], x2 = x[node * 3 + 2];
    float h1[32];
#pragma unroll
    for (int j = 0; j < 32; j++)
        h1[j] = fmaxf(sb1[j] + x0 * sw1[j] + x1 * sw1[32 + j] + x2 * sw1[64 + j], 0.0f);

    float acc[64];
#pragma unroll
    for (int j = 0; j < 64; j++) acc[j] = sb2[j];
    for (int k = 0; k < 32; k++) {
        float hk = h1[k];
#pragma unroll
        for (int j4 = 0; j4 < 16; j4++) {
            float4 w = *(const float4*)&sw2[k * 64 + j4 * 4];
            acc[j4 * 4 + 0] = fmaf(hk, w.x, acc[j4 * 4 + 0]);
            acc[j4 * 4 + 1] = fmaf(hk, w.y, acc[j4 * 4 + 1]);
            acc[j4 * 4 + 2] = fmaf(hk, w.z, acc[j4 * 4 + 2]);
            acc[j4 * 4 + 3] = fmaf(hk, w.w, acc[j4 * 4 + 3]);
        }
    }
#pragma unroll
    for (int j4 = 0; j4 < 16; j4++) {
        ushort4 h4, l4;
        unsigned short* hp = (unsigned short*)&h4;
        unsigned short* lp = (unsigned short*)&l4;
#pragma unroll
        for (int t = 0; t < 4; t++) {
            float v = fmaxf(acc[j4 * 4 + t], 0.0f);
            unsigned short h = bf16h(v);
            hp[t] = h;
            lp[t] = bf16h(v - bf16f(h));
        }
        *(ushort4*)&H2h[(size_t)node * 64 + j4 * 4] = h4;
        *(ushort4*)&H2l[(size_t)node * 64 + j4 * 4] = l4;
    }
}

// ---------------- MFMA GEMM, double-bf16, 4-plane staging -------------------
// C[M,N] = (Ah+Al)[M,K] @ (Bh+Bl)[K,N]  ~=  AhBh + AhBl + AlBh.
// Bt[N][2K] = [Bh;Bl]. BK=32. Block = WAVES*64 threads, tile BM x BN.
// AF16: A is a single fp16 plane (arg Ah); hi/lo split done in registers.
// MODE 0: Cf=relu(C+bias). MODE 1: relu(C+bias) -> Ch/Cl bf16 planes.
// MODE 2: Cf=C. MODE 3: fp16(relu(C+bias)) -> Ch. MODE 4: fp16(C) -> Ch.

template<int BM, int BN, int WAVES, int WGR, int WGC, int WRF, int WCF, int MODE, bool AF16>
__global__ __launch_bounds__(WAVES * 64) void gemm_mfma_kernel(
        const unsigned short* __restrict__ Ah, const unsigned short* __restrict__ Al,
        const unsigned short* __restrict__ Bt, const float* __restrict__ bias,
        float* __restrict__ Cf, unsigned short* __restrict__ Ch,
        unsigned short* __restrict__ Cl, int M, int K, int N) {
    static_assert(WGR * WRF * 16 == BM, "row cover");
    static_assert(WGC * WCF * 16 == BN, "col cover");
    static_assert(WGR * WGC == WAVES, "wave grid");
    constexpr int AUNITS = AF16 ? (BM / 16) : (BM / 8);
    constexpr int BUNITS = BN / 8;
    static_assert(AUNITS % WAVES == 0 && BUNITS % WAVES == 0, "staging split");
    __shared__ __align__(16) unsigned short Ash[BM * 32];
    __shared__ __align__(16) unsigned short Asl[AF16 ? 16 : BM * 32];
    __shared__ __align__(16) unsigned short Bsh[BN * 32];
    __shared__ __align__(16) unsigned short Bsl[BN * 32];

    const int tid  = threadIdx.x;
    const int lane = tid & 63;
    const int wave = tid >> 6;
    const int bm = blockIdx.y * BM;
    const int bn = blockIdx.x * BN;
    const int K2 = 2 * K;

    const int wr0 = (wave / WGC) * (WRF * 16);
    const int wc0 = (wave % WGC) * (WCF * 16);
    const int lr   = lane & 15;
    const int quad = lane >> 4;
    const int arow = lane >> 2;          // row within 16-row group
    const int acol = (lane & 3) * 8;     // halves within 32-half row

    floatx4 acc[WRF][WCF];
#pragma unroll
    for (int i = 0; i < WRF; i++)
#pragma unroll
        for (int j = 0; j < WCF; j++) acc[i][j] = floatx4{0.f, 0.f, 0.f, 0.f};

    for (int k0 = 0; k0 < K; k0 += 32) {
        // A staging
#pragma unroll
        for (int u = 0; u < AUNITS / WAVES; u++) {
            int unit = wave + u * WAVES;
            if (AF16) {
                int grp = unit;
                int gm = bm + grp * 16 + arow;
                if (gm >= M) gm = M - 1;
                gld_lds16(&Ash[grp * 512], Ah + (size_t)gm * K + k0 + acol);
            } else {
                int grp = unit >> 1, pl = unit & 1;
                int gm = bm + grp * 16 + arow;
                if (gm >= M) gm = M - 1;     // clamp: garbage rows discarded at store
                size_t go = (size_t)gm * K + k0 + acol;
                if (pl) gld_lds16(&Asl[grp * 512], Al + go);
                else    gld_lds16(&Ash[grp * 512], Ah + go);
            }
        }
        // B staging: BN/16 col-groups x 2 planes
#pragma unroll
        for (int u = 0; u < BUNITS / WAVES; u++) {
            int unit = wave + u * WAVES;
            int grp = unit >> 1, pl = unit & 1;
            int gr = bn + grp * 16 + arow;
            size_t go = (size_t)gr * K2 + k0 + acol + (pl ? K : 0);
            if (pl) gld_lds16(&Bsl[grp * 512], Bt + go);
            else    gld_lds16(&Bsh[grp * 512], Bt + go);
        }
        __syncthreads();

        short8 ahf[WRF], alf[WRF], bhf[WCF], blf[WCF];
#pragma unroll
        for (int i = 0; i < WRF; i++) {
            int ro = (wr0 + i * 16 + lr) * 32 + quad * 8;
            if (AF16) {
                half8 av = *reinterpret_cast<const half8*>(&Ash[ro]);
#pragma unroll
                for (int t = 0; t < 8; t++) {
                    float f = (float)av[t];
                    unsigned short h = bf16h(f);
                    ahf[i][t] = (short)h;
                    alf[i][t] = (short)bf16h(f - bf16f(h));
                }
            } else {
                ahf[i] = *reinterpret_cast<const short8*>(&Ash[ro]);
                alf[i] = *reinterpret_cast<const short8*>(&Asl[ro]);
            }
        }
#pragma unroll
        for (int j = 0; j < WCF; j++) {
            int ro = (wc0 + j * 16 + lr) * 32 + quad * 8;
            bhf[j] = *reinterpret_cast<const short8*>(&Bsh[ro]);
            blf[j] = *reinterpret_cast<const short8*>(&Bsl[ro]);
        }
#pragma unroll
        for (int i = 0; i < WRF; i++)
#pragma unroll
            for (int j = 0; j < WCF; j++) {
                acc[i][j] = __builtin_amdgcn_mfma_f32_16x16x32_bf16(
                    ahf[i], bhf[j], acc[i][j], 0, 0, 0);
                acc[i][j] = __builtin_amdgcn_mfma_f32_16x16x32_bf16(
                    ahf[i], blf[j], acc[i][j], 0, 0, 0);
                acc[i][j] = __builtin_amdgcn_mfma_f32_16x16x32_bf16(
                    alf[i], bhf[j], acc[i][j], 0, 0, 0);
            }
        __syncthreads();
    }

    // epilogue: C/D layout col=lane&15, row=quad*4+reg (m89-verified)
#pragma unroll
    for (int i = 0; i < WRF; i++) {
#pragma unroll
        for (int j = 0; j < WCF; j++) {
            int gc = bn + wc0 + j * 16 + lr;
#pragma unroll
            for (int reg = 0; reg < 4; reg++) {
                int gr = bm + wr0 + i * 16 + quad * 4 + reg;
                if (gr >= M) continue;
                float v = acc[i][j][reg];
                if (MODE == 0) {
                    v = fmaxf(v + bias[gc], 0.0f);
                    Cf[(size_t)gr * N + gc] = v;
                } else if (MODE == 1) {
                    v = fmaxf(v + bias[gc], 0.0f);
                    unsigned short h = bf16h(v);
                    unsigned short l = bf16h(v - bf16f(h));
                    Ch[(size_t)gr * N + gc] = h;
                    Cl[(size_t)gr * N + gc] = l;
                } else if (MODE == 2) {
                    Cf[(size_t)gr * N + gc] = v;
                } else if (MODE == 3) {  // fp16 activation store
                    v = fmaxf(v + bias[gc], 0.0f);
                    ((_Float16*)Ch)[(size_t)gr * N + gc] = (_Float16)v;
                } else {                 // MODE 4: fp16 raw store
                    ((_Float16*)Ch)[(size_t)gr * N + gc] = (_Float16)v;
                }
            }
        }
    }
}

// ---------------- aggregation from fp16 table: thread per (node, half8) -----

template<int F>
__global__ void agg_f16_kernel(const _Float16* __restrict__ table,
                               const int* __restrict__ offsets,
                               const int* __restrict__ ssrc,
                               const float* __restrict__ snorm,
                               const float* __restrict__ dinv,
                               unsigned short* __restrict__ Ah,
                               unsigned short* __restrict__ Al, int n) {
    constexpr int F8 = F / 8;
    int gid = blockIdx.x * blockDim.x + threadIdx.x;
    if (gid >= n * F8) return;
    int node = gid / F8;                 // F8 pow2 -> shift
    int c8 = (gid - node * F8) * 8;

    float acc[8];
#pragma unroll
    for (int i = 0; i < 8; i++) acc[i] = 0.0f;

    int beg = offsets[node], end = offsets[node + 1];
    for (int e = beg; e < end; ++e) {
        int s = ssrc[e];
        float w = snorm[e];
        half8 r = *reinterpret_cast<const half8*>(table + (size_t)s * F + c8);
#pragma unroll
        for (int i = 0; i < 8; i++) acc[i] = fmaf((float)r[i], w, acc[i]);
    }
    float dv = dinv[node];
    float sw = dv * dv;
    half8 r = *reinterpret_cast<const half8*>(table + (size_t)node * F + c8);
#pragma unroll
    for (int i = 0; i < 8; i++) acc[i] = fmaf((float)r[i], sw, acc[i]);

    unsigned short hb[8], lb[8];
#pragma unroll
    for (int i = 0; i < 8; i++) {
        unsigned short h = bf16h(acc[i]);
        hb[i] = h;
        lb[i] = bf16h(acc[i] - bf16f(h));
    }
    *(uint4*)&Ah[(size_t)node * F + c8] = *(uint4*)hb;
    *(uint4*)&Al[(size_t)node * F + c8] = *(uint4*)lb;
}

// ---------------- fused final aggregation + softmax: one wave per node ------
// z[N,64] fp16 (cols 50..63 zero); out[N,50] = softmax(AGG(z)+bias).

__global__ void agg50_softmax_kernel(const _Float16* __restrict__ z,
                                     const int* __restrict__ offsets,
                                     const int* __restrict__ ssrc,
                                     const float* __restrict__ snorm,
                                     const float* __restrict__ dinv,
                                     const float* __restrict__ bias,
                                     float* __restrict__ out, int n) {
    int node = blockIdx.x * 4 + (threadIdx.x >> 6);
    int lane = threadIdx.x & 63;
    if (node >= n) return;

    float a = 0.0f;
    int beg = offsets[node], end = offsets[node + 1];
    for (int e = beg; e < end; ++e) {
        int s = ssrc[e];
        a = fmaf((float)z[(size_t)s * 64 + lane], snorm[e], a);
    }
    float dv = dinv[node];
    a = fmaf((float)z[(size_t)node * 64 + lane], dv * dv, a);

    float v = (lane < 50) ? a + bias[lane] : -INFINITY;
    float m = v;
#pragma unroll
    for (int off = 32; off > 0; off >>= 1) m = fmaxf(m, __shfl_xor(m, off));
    float e = (lane < 50) ? expf(v - m) : 0.0f;
    float s = e;
#pragma unroll
    for (int off = 32; off > 0; off >>= 1) s += __shfl_xor(s, off);
    if (lane < 50) out[(size_t)node * 50 + lane] = e / s;
}

// ---------------------------------------------------------------------------

extern "C" void kernel_launch(void* const* d_in, const int* in_sizes, int n_in,
                              void* d_out, int out_size, void* d_ws, size_t ws_size,
                              hipStream_t stream) {
    const float* x    = (const float*)d_in[0];
    const int*   ei   = (const int*)  d_in[1];
    const float* w1   = (const float*)d_in[2];
    const float* b1   = (const float*)d_in[3];
    const float* w2   = (const float*)d_in[4];
    const float* b2   = (const float*)d_in[5];
    const float* w3   = (const float*)d_in[6];
    const float* b3   = (const float*)d_in[7];
    const float* g1w  = (const float*)d_in[8];
    const float* g1b  = (const float*)d_in[9];
    const float* g2w  = (const float*)d_in[10];
    const float* g2b  = (const float*)d_in[11];
    const float* g3w  = (const float*)d_in[12];
    const float* g3b  = (const float*)d_in[13];
    float* out = (float*)d_out;

    const int N = in_sizes[0] / 3;      // 50000
    const int E = in_sizes[1] / 2;      // 800000
    const int* src = ei;
    const int* dst = ei + E;
    const int NB = (N + 255) / 256;     // 196

    // ---- workspace arena with liveness-based region reuse ----
    char* ws = (char*)d_ws;
    size_t off = 0;
    auto alloc = [&](size_t bytes) -> char* {
        char* p = ws + off;
        off = (off + bytes + 255) & ~(size_t)255;
        return p;
    };
    int*   counts  = (int*)  alloc((size_t)N * 4);
    int*   offsets = (int*)  alloc((size_t)(N + 1) * 4);
    int*   cursor  = (int*)  alloc((size_t)N * 4);
    float* dinv    = (float*)alloc((size_t)N * 4);
    int*   bsum    = (int*)  alloc((size_t)256 * 4);
    int*   bsumx   = (int*)  alloc((size_t)256 * 4);
    int*   ssrc    = (int*)  alloc((size_t)E * 4);
    float* snorm   = (float*)alloc((size_t)E * 4);
    unsigned short* Bt1 = (unsigned short*)alloc((size_t)256 * 256 * 2);
    unsigned short* Bt2 = (unsigned short*)alloc((size_t)512 * 512 * 2);
    unsigned short* Bt3 = (unsigned short*)alloc((size_t)64 * 1024 * 2);
    unsigned short* Bt0 = (unsigned short*)alloc((size_t)128 * 128 * 2);
    char* R1 = alloc((size_t)N * 256 * 4);   // 51.2 MB
    char* R2 = alloc((size_t)N * 256 * 4);   // 51.2 MB
    char* R3 = alloc((size_t)N * 512 * 2);   // 51.2 MB (A512 fp16)
    (void)ws_size;

    // R1 phase 1: S128f16 [N,128] fp16 | A128h | A128l   phase 2: A256h|A256l
    _Float16*       S128f = (_Float16*)R1;
    unsigned short* A128h = (unsigned short*)(R1 + (size_t)N * 128 * 2);
    unsigned short* A128l = (unsigned short*)(R1 + (size_t)N * 128 * 4);
    unsigned short* A256h = (unsigned short*)R1;
    unsigned short* A256l = (unsigned short*)(R1 + (size_t)N * 256 * 2);
    // R2 phase 1: H2h|H2l [N,64] bf16   phase 2: G1f16 [N,256] fp16
    // phase 3: zbuf [N,64] fp16
    unsigned short* H2h  = (unsigned short*)R2;
    unsigned short* H2l  = (unsigned short*)(R2 + (size_t)N * 64 * 2);
    _Float16*       G1f  = (_Float16*)R2;
    _Float16*       zbuf = (_Float16*)R2;
    // R3: A512f fp16 [N,512]
    _Float16*       A512f = (_Float16*)R3;

    // ---- degree + CSR + weight prep ----
    hipMemsetAsync(counts, 0, (size_t)N * 4, stream);
    hist_kernel<<<(E + 255) / 256, 256, 0, stream>>>(dst, counts, E);
    scan1_kernel<<<NB, 256, 0, stream>>>(counts, bsum, N);
    scan2_kernel<<<1, 256, 0, stream>>>(bsum, bsumx, offsets, NB, N);
    scan3_kernel<<<NB, 256, 0, stream>>>(counts, bsumx, offsets, cursor, dinv, N);
    fill_kernel<<<(E + 255) / 256, 256, 0, stream>>>(src, dst, dinv, cursor, ssrc, snorm, E);
    prepw_kernel<<<(204800 + 255) / 256, 256, 0, stream>>>(
        g1w, g2w, g3w, w3, Bt1, Bt2, Bt3, Bt0);

    const int MB = (N + 127) / 128;     // 391 row-blocks (BM=128)
    const int MB64 = (N + 63) / 64;     // 782 row-blocks (BM=64)

    // ---- MLP: x -> h2 hi/lo (fused), h2 -> h3 fp16 table (MFMA, K=64) ----
    mlp12_kernel<<<NB, 256, 0, stream>>>(x, w1, b1, w2, b2, H2h, H2l, N);
    {   dim3 grid(1, MB);
        gemm_mfma_kernel<128, 128, 4, 2, 2, 4, 4, 3, false><<<grid, 256, 0, stream>>>(
            H2h, H2l, Bt0, b3, nullptr, (unsigned short*)S128f, nullptr, N, 64, 128);
    }

    // ---- GCN1: agg@128 (fp16 table) -> MFMA 128->256 BN=128 (fp16 out) ----
    agg_f16_kernel<128><<<((size_t)N * 16 + 255) / 256, 256, 0, stream>>>(
        S128f, offsets, ssrc, snorm, dinv, A128h, A128l, N);
    {   dim3 grid(2, MB);
        gemm_mfma_kernel<128, 128, 4, 2, 2, 4, 4, 3, false><<<grid, 256, 0, stream>>>(
            A128h, A128l, Bt1, g1b, nullptr, (unsigned short*)G1f, nullptr, N, 128, 256);
    }

    // ---- GCN2: agg@256 (fp16 table) -> MFMA 256->512 BN=128 (fp16 out) ----
    agg_f16_kernel<256><<<((size_t)N * 32 + 255) / 256, 256, 0, stream>>>(
        G1f, offsets, ssrc, snorm, dinv, A256h, A256l, N);
    {   dim3 grid(4, MB);
        gemm_mfma_kernel<128, 128, 4, 2, 2, 4, 4, 3, false><<<grid, 256, 0, stream>>>(
            A256h, A256l, Bt2, g2b, nullptr, (unsigned short*)A512f, nullptr, N, 256, 512);
    }

    // ---- GCN3: MFMA 512->64 BM=64 AF16 (fp16 out) -> fused agg + softmax ----
    {   dim3 grid(1, MB64);
        gemm_mfma_kernel<64, 64, 4, 4, 1, 1, 4, 4, true><<<grid, 256, 0, stream>>>(
            (const unsigned short*)A512f, nullptr, Bt3, nullptr,
            nullptr, (unsigned short*)zbuf, nullptr, N, 512, 64);
    }
    agg50_softmax_kernel<<<(N + 3) / 4, 256, 0, stream>>>(
        zbuf, offsets, ssrc, snorm, dinv, g3b, out, N);
}

// Round 11
// 489.727 us; speedup vs baseline: 1.1517x; 1.0584x over previous
//
#include <hip/hip_runtime.h>
#include <hip/hip_bf16.h>
#include <math.h>

// ---------------------------------------------------------------------------
// GCN part-seg pipeline.
// R11: agg50_softmax edge loop unrolled 4x with independent accumulators --
//      counters (FETCH 37MB, HBM 7%, VALU 23%) showed it is L2-latency-bound,
//      the regime where MLP unrolling pays (unlike the fabric-bound agg@256).
//      Everything else identical to R10.
// ---------------------------------------------------------------------------

typedef __attribute__((ext_vector_type(8))) short short8;     // 8 bf16
typedef __attribute__((ext_vector_type(8))) _Float16 half8;   // 8 fp16
typedef __attribute__((ext_vector_type(4))) float floatx4;    // 4 fp32

__device__ __forceinline__ unsigned short bf16h(float f) {
    unsigned int u = __float_as_uint(f);
    u += 0x7fff + ((u >> 16) & 1);          // round-to-nearest-even
    return (unsigned short)(u >> 16);
}
__device__ __forceinline__ float bf16f(unsigned short h) {
    return __uint_as_float(((unsigned int)h) << 16);
}

__device__ __forceinline__ void gld_lds16(unsigned short* lds, const unsigned short* g) {
    __builtin_amdgcn_global_load_lds(
        (const __attribute__((address_space(1))) unsigned int*)g,
        (__attribute__((address_space(3))) unsigned int*)lds, 16, 0, 0);
}

// ---------------- degree / CSR build ----------------

__global__ void hist_kernel(const int* __restrict__ dst, int* __restrict__ counts, int e) {
    int g = blockIdx.x * blockDim.x + threadIdx.x;
    if (g < e) atomicAdd(&counts[dst[g]], 1);
}

__global__ void scan1_kernel(const int* __restrict__ counts, int* __restrict__ bsum, int n) {
    __shared__ int buf[256];
    int i = blockIdx.x * 256 + threadIdx.x;
    buf[threadIdx.x] = (i < n) ? counts[i] : 0;
    __syncthreads();
    for (int off = 128; off > 0; off >>= 1) {
        if (threadIdx.x < off) buf[threadIdx.x] += buf[threadIdx.x + off];
        __syncthreads();
    }
    if (threadIdx.x == 0) bsum[blockIdx.x] = buf[0];
}

__global__ void scan2_kernel(const int* __restrict__ bsum, int* __restrict__ bsumx,
                             int* __restrict__ offsets, int nb, int n) {
    __shared__ int buf[256];
    int tid = threadIdx.x;
    int v = (tid < nb) ? bsum[tid] : 0;
    buf[tid] = v;
    __syncthreads();
    for (int off = 1; off < 256; off <<= 1) {
        int t = (tid >= off) ? buf[tid - off] : 0;
        __syncthreads();
        buf[tid] += t;
        __syncthreads();
    }
    if (tid < nb) bsumx[tid] = buf[tid] - v;       // exclusive
    if (tid == 255) offsets[n] = buf[255];          // total
}

__global__ void scan3_kernel(const int* __restrict__ counts, const int* __restrict__ bsumx,
                             int* __restrict__ offsets, int* __restrict__ cursor,
                             float* __restrict__ dinv, int n) {
    __shared__ int buf[256];
    int tid = threadIdx.x;
    int i = blockIdx.x * 256 + tid;
    int c = (i < n) ? counts[i] : 0;
    buf[tid] = c;
    __syncthreads();
    for (int off = 1; off < 256; off <<= 1) {
        int t = (tid >= off) ? buf[tid - off] : 0;
        __syncthreads();
        buf[tid] += t;
        __syncthreads();
    }
    if (i < n) {
        int excl = bsumx[blockIdx.x] + buf[tid] - c;
        offsets[i] = excl;
        cursor[i] = excl;
        dinv[i] = rsqrtf((float)c + 1.0f);
    }
}

__global__ void fill_kernel(const int* __restrict__ src, const int* __restrict__ dst,
                            const float* __restrict__ dinv, int* __restrict__ cursor,
                            int* __restrict__ ssrc, float* __restrict__ snorm, int e) {
    int g = blockIdx.x * blockDim.x + threadIdx.x;
    if (g >= e) return;
    int s = src[g], d = dst[g];
    int pos = atomicAdd(&cursor[d], 1);
    ssrc[pos]  = s;
    snorm[pos] = dinv[s] * dinv[d];
}

// ---------------- fused weight prep: W[K][N] fp32 -> Bt[N][2K] = [Bh;Bl] ----

__device__ __forceinline__ void wsplit_one(float w, unsigned short* Bt, int k, int n, int K) {
    unsigned short h = bf16h(w);
    unsigned short l = bf16h(w - bf16f(h));
    size_t base = (size_t)n * (2 * K);
    Bt[base + k]     = h;
    Bt[base + K + k] = l;
}

__global__ void prepw_kernel(const float* __restrict__ g1w, const float* __restrict__ g2w,
                             const float* __restrict__ g3w, const float* __restrict__ w3,
                             unsigned short* __restrict__ Bt1,
                             unsigned short* __restrict__ Bt2,
                             unsigned short* __restrict__ Bt3,
                             unsigned short* __restrict__ Bt0) {
    int gid = blockIdx.x * blockDim.x + threadIdx.x;
    if (gid < 32768) {                       // g1: K=128, N=256
        int k = gid >> 8, n = gid & 255;
        wsplit_one(g1w[gid], Bt1, k, n, 128);
    } else if (gid < 32768 + 131072) {       // g2: K=256, N=512
        int idx = gid - 32768;
        int k = idx >> 9, n = idx & 511;
        wsplit_one(g2w[idx], Bt2, k, n, 256);
    } else if (gid < 32768 + 131072 + 32768) { // g3 padded: K=512, N=64
        int idx = gid - 32768 - 131072;
        int k = idx >> 6, c = idx & 63;
        float w = (c < 50) ? g3w[k * 50 + c] : 0.0f;
        wsplit_one(w, Bt3, k, c, 512);
    } else if (gid < 32768 + 131072 + 32768 + 8192) { // w3: K=64, N=128
        int idx = gid - 32768 - 131072 - 32768;
        int k = idx >> 7, n = idx & 127;
        wsplit_one(w3[idx], Bt0, k, n, 64);
    }
}

// ---------------- fused MLP layers 1+2: x[N,3] -> h2 hi/lo bf16 planes ------

__global__ __launch_bounds__(256) void mlp12_kernel(
        const float* __restrict__ x,
        const float* __restrict__ w1, const float* __restrict__ b1,
        const float* __restrict__ w2, const float* __restrict__ b2,
        unsigned short* __restrict__ H2h, unsigned short* __restrict__ H2l, int n) {
    __shared__ float sw1[96], sb1[32], sw2[2048], sb2[64];
    int tid = threadIdx.x;
    if (tid < 96) sw1[tid] = w1[tid];
    if (tid < 32) sb1[tid] = b1[tid];
    if (tid < 64) sb2[tid] = b2[tid];
    for (int i = tid; i < 2048; i += 256) sw2[i] = w2[i];
    __syncthreads();

    int node = blockIdx.x * 256 + tid;
    if (node >= n) return;
    float x0 = x[node * 3 + 0], x1 = x[node * 3 + 1], x2 = x[node * 3 + 2];
    float h1[32];
#pragma unroll
    for (int j = 0; j < 32; j++)
        h1[j] = fmaxf(sb1[j] + x0 * sw1[j] + x1 * sw1[32 + j] + x2 * sw1[64 + j], 0.0f);

    float acc[64];
#pragma unroll
    for (int j = 0; j < 64; j++) acc[j] = sb2[j];
    for (int k = 0; k < 32; k++) {
        float hk = h1[k];
#pragma unroll
        for (int j4 = 0; j4 < 16; j4++) {
            float4 w = *(const float4*)&sw2[k * 64 + j4 * 4];
            acc[j4 * 4 + 0] = fmaf(hk, w.x, acc[j4 * 4 + 0]);
            acc[j4 * 4 + 1] = fmaf(hk, w.y, acc[j4 * 4 + 1]);
            acc[j4 * 4 + 2] = fmaf(hk, w.z, acc[j4 * 4 + 2]);
            acc[j4 * 4 + 3] = fmaf(hk, w.w, acc[j4 * 4 + 3]);
        }
    }
#pragma unroll
    for (int j4 = 0; j4 < 16; j4++) {
        ushort4 h4, l4;
        unsigned short* hp = (unsigned short*)&h4;
        unsigned short* lp = (unsigned short*)&l4;
#pragma unroll
        for (int t = 0; t < 4; t++) {
            float v = fmaxf(acc[j4 * 4 + t], 0.0f);
            unsigned short h = bf16h(v);
            hp[t] = h;
            lp[t] = bf16h(v - bf16f(h));
        }
        *(ushort4*)&H2h[(size_t)node * 64 + j4 * 4] = h4;
        *(ushort4*)&H2l[(size_t)node * 64 + j4 * 4] = l4;
    }
}

// ---------------- MFMA GEMM, double-bf16, 4-plane staging -------------------
// C[M,N] = (Ah+Al)[M,K] @ (Bh+Bl)[K,N]  ~=  AhBh + AhBl + AlBh.
// Bt[N][2K] = [Bh;Bl]. BK=32. Block = WAVES*64 threads, tile BM x BN.
// AF16: A is a single fp16 plane (arg Ah); hi/lo split done in registers.
// MODE 0: Cf=relu(C+bias). MODE 1: relu(C+bias) -> Ch/Cl bf16 planes.
// MODE 2: Cf=C. MODE 3: fp16(relu(C+bias)) -> Ch. MODE 4: fp16(C) -> Ch.

template<int BM, int BN, int WAVES, int WGR, int WGC, int WRF, int WCF, int MODE, bool AF16>
__global__ __launch_bounds__(WAVES * 64) void gemm_mfma_kernel(
        const unsigned short* __restrict__ Ah, const unsigned short* __restrict__ Al,
        const unsigned short* __restrict__ Bt, const float* __restrict__ bias,
        float* __restrict__ Cf, unsigned short* __restrict__ Ch,
        unsigned short* __restrict__ Cl, int M, int K, int N) {
    static_assert(WGR * WRF * 16 == BM, "row cover");
    static_assert(WGC * WCF * 16 == BN, "col cover");
    static_assert(WGR * WGC == WAVES, "wave grid");
    constexpr int AUNITS = AF16 ? (BM / 16) : (BM / 8);
    constexpr int BUNITS = BN / 8;
    static_assert(AUNITS % WAVES == 0 && BUNITS % WAVES == 0, "staging split");
    __shared__ __align__(16) unsigned short Ash[BM * 32];
    __shared__ __align__(16) unsigned short Asl[AF16 ? 16 : BM * 32];
    __shared__ __align__(16) unsigned short Bsh[BN * 32];
    __shared__ __align__(16) unsigned short Bsl[BN * 32];

    const int tid  = threadIdx.x;
    const int lane = tid & 63;
    const int wave = tid >> 6;
    const int bm = blockIdx.y * BM;
    const int bn = blockIdx.x * BN;
    const int K2 = 2 * K;

    const int wr0 = (wave / WGC) * (WRF * 16);
    const int wc0 = (wave % WGC) * (WCF * 16);
    const int lr   = lane & 15;
    const int quad = lane >> 4;
    const int arow = lane >> 2;          // row within 16-row group
    const int acol = (lane & 3) * 8;     // halves within 32-half row

    floatx4 acc[WRF][WCF];
#pragma unroll
    for (int i = 0; i < WRF; i++)
#pragma unroll
        for (int j = 0; j < WCF; j++) acc[i][j] = floatx4{0.f, 0.f, 0.f, 0.f};

    for (int k0 = 0; k0 < K; k0 += 32) {
        // A staging
#pragma unroll
        for (int u = 0; u < AUNITS / WAVES; u++) {
            int unit = wave + u * WAVES;
            if (AF16) {
                int grp = unit;
                int gm = bm + grp * 16 + arow;
                if (gm >= M) gm = M - 1;
                gld_lds16(&Ash[grp * 512], Ah + (size_t)gm * K + k0 + acol);
            } else {
                int grp = unit >> 1, pl = unit & 1;
                int gm = bm + grp * 16 + arow;
                if (gm >= M) gm = M - 1;     // clamp: garbage rows discarded at store
                size_t go = (size_t)gm * K + k0 + acol;
                if (pl) gld_lds16(&Asl[grp * 512], Al + go);
                else    gld_lds16(&Ash[grp * 512], Ah + go);
            }
        }
        // B staging: BN/16 col-groups x 2 planes
#pragma unroll
        for (int u = 0; u < BUNITS / WAVES; u++) {
            int unit = wave + u * WAVES;
            int grp = unit >> 1, pl = unit & 1;
            int gr = bn + grp * 16 + arow;
            size_t go = (size_t)gr * K2 + k0 + acol + (pl ? K : 0);
            if (pl) gld_lds16(&Bsl[grp * 512], Bt + go);
            else    gld_lds16(&Bsh[grp * 512], Bt + go);
        }
        __syncthreads();

        short8 ahf[WRF], alf[WRF], bhf[WCF], blf[WCF];
#pragma unroll
        for (int i = 0; i < WRF; i++) {
            int ro = (wr0 + i * 16 + lr) * 32 + quad * 8;
            if (AF16) {
                half8 av = *reinterpret_cast<const half8*>(&Ash[ro]);
#pragma unroll
                for (int t = 0; t < 8; t++) {
                    float f = (float)av[t];
                    unsigned short h = bf16h(f);
                    ahf[i][t] = (short)h;
                    alf[i][t] = (short)bf16h(f - bf16f(h));
                }
            } else {
                ahf[i] = *reinterpret_cast<const short8*>(&Ash[ro]);
                alf[i] = *reinterpret_cast<const short8*>(&Asl[ro]);
            }
        }
#pragma unroll
        for (int j = 0; j < WCF; j++) {
            int ro = (wc0 + j * 16 + lr) * 32 + quad * 8;
            bhf[j] = *reinterpret_cast<const short8*>(&Bsh[ro]);
            blf[j] = *reinterpret_cast<const short8*>(&Bsl[ro]);
        }
#pragma unroll
        for (int i = 0; i < WRF; i++)
#pragma unroll
            for (int j = 0; j < WCF; j++) {
                acc[i][j] = __builtin_amdgcn_mfma_f32_16x16x32_bf16(
                    ahf[i], bhf[j], acc[i][j], 0, 0, 0);
                acc[i][j] = __builtin_amdgcn_mfma_f32_16x16x32_bf16(
                    ahf[i], blf[j], acc[i][j], 0, 0, 0);
                acc[i][j] = __builtin_amdgcn_mfma_f32_16x16x32_bf16(
                    alf[i], bhf[j], acc[i][j], 0, 0, 0);
            }
        __syncthreads();
    }

    // epilogue: C/D layout col=lane&15, row=quad*4+reg (m89-verified)
#pragma unroll
    for (int i = 0; i < WRF; i++) {
#pragma unroll
        for (int j = 0; j < WCF; j++) {
            int gc = bn + wc0 + j * 16 + lr;
#pragma unroll
            for (int reg = 0; reg < 4; reg++) {
                int gr = bm + wr0 + i * 16 + quad * 4 + reg;
                if (gr >= M) continue;
                float v = acc[i][j][reg];
                if (MODE == 0) {
                    v = fmaxf(v + bias[gc], 0.0f);
                    Cf[(size_t)gr * N + gc] = v;
                } else if (MODE == 1) {
                    v = fmaxf(v + bias[gc], 0.0f);
                    unsigned short h = bf16h(v);
                    unsigned short l = bf16h(v - bf16f(h));
                    Ch[(size_t)gr * N + gc] = h;
                    Cl[(size_t)gr * N + gc] = l;
                } else if (MODE == 2) {
                    Cf[(size_t)gr * N + gc] = v;
                } else if (MODE == 3) {  // fp16 activation store
                    v = fmaxf(v + bias[gc], 0.0f);
                    ((_Float16*)Ch)[(size_t)gr * N + gc] = (_Float16)v;
                } else {                 // MODE 4: fp16 raw store
                    ((_Float16*)Ch)[(size_t)gr * N + gc] = (_Float16)v;
                }
            }
        }
    }
}

// ---------------- aggregation from fp16 table: thread per (node, half8) -----

template<int F>
__global__ void agg_f16_kernel(const _Float16* __restrict__ table,
                               const int* __restrict__ offsets,
                               const int* __restrict__ ssrc,
                               const float* __restrict__ snorm,
                               const float* __restrict__ dinv,
                               unsigned short* __restrict__ Ah,
                               unsigned short* __restrict__ Al, int n) {
    constexpr int F8 = F / 8;
    int gid = blockIdx.x * blockDim.x + threadIdx.x;
    if (gid >= n * F8) return;
    int node = gid / F8;                 // F8 pow2 -> shift
    int c8 = (gid - node * F8) * 8;

    float acc[8];
#pragma unroll
    for (int i = 0; i < 8; i++) acc[i] = 0.0f;

    int beg = offsets[node], end = offsets[node + 1];
    for (int e = beg; e < end; ++e) {
        int s = ssrc[e];
        float w = snorm[e];
        half8 r = *reinterpret_cast<const half8*>(table + (size_t)s * F + c8);
#pragma unroll
        for (int i = 0; i < 8; i++) acc[i] = fmaf((float)r[i], w, acc[i]);
    }
    float dv = dinv[node];
    float sw = dv * dv;
    half8 r = *reinterpret_cast<const half8*>(table + (size_t)node * F + c8);
#pragma unroll
    for (int i = 0; i < 8; i++) acc[i] = fmaf((float)r[i], sw, acc[i]);

    unsigned short hb[8], lb[8];
#pragma unroll
    for (int i = 0; i < 8; i++) {
        unsigned short h = bf16h(acc[i]);
        hb[i] = h;
        lb[i] = bf16h(acc[i] - bf16f(h));
    }
    *(uint4*)&Ah[(size_t)node * F + c8] = *(uint4*)hb;
    *(uint4*)&Al[(size_t)node * F + c8] = *(uint4*)lb;
}

// ---------------- fused final aggregation + softmax: one wave per node ------
// z[N,64] fp16 (cols 50..63 zero); out[N,50] = softmax(AGG(z)+bias).
// Edge loop unrolled 4x, independent accumulators: 4 row-gathers in flight
// (L2-latency-bound regime -- FETCH 37MB << logical 102MB, HBM 7%).

__global__ void agg50_softmax_kernel(const _Float16* __restrict__ z,
                                     const int* __restrict__ offsets,
                                     const int* __restrict__ ssrc,
                                     const float* __restrict__ snorm,
                                     const float* __restrict__ dinv,
                                     const float* __restrict__ bias,
                                     float* __restrict__ out, int n) {
    int node = blockIdx.x * 4 + (threadIdx.x >> 6);
    int lane = threadIdx.x & 63;
    if (node >= n) return;

    float a0 = 0.f, a1 = 0.f, a2 = 0.f, a3 = 0.f;
    int beg = offsets[node], end = offsets[node + 1];
    int e = beg;
    for (; e + 4 <= end; e += 4) {
        int s0 = ssrc[e + 0], s1 = ssrc[e + 1], s2 = ssrc[e + 2], s3 = ssrc[e + 3];
        float w0 = snorm[e + 0], w1 = snorm[e + 1];
        float w2 = snorm[e + 2], w3 = snorm[e + 3];
        float r0 = (float)z[(size_t)s0 * 64 + lane];
        float r1 = (float)z[(size_t)s1 * 64 + lane];
        float r2 = (float)z[(size_t)s2 * 64 + lane];
        float r3 = (float)z[(size_t)s3 * 64 + lane];
        a0 = fmaf(r0, w0, a0);
        a1 = fmaf(r1, w1, a1);
        a2 = fmaf(r2, w2, a2);
        a3 = fmaf(r3, w3, a3);
    }
    for (; e < end; ++e)
        a0 = fmaf((float)z[(size_t)ssrc[e] * 64 + lane], snorm[e], a0);

    float dv = dinv[node];
    float a = fmaf((float)z[(size_t)node * 64 + lane], dv * dv,
                   (a0 + a1) + (a2 + a3));

    float v = (lane < 50) ? a + bias[lane] : -INFINITY;
    float m = v;
#pragma unroll
    for (int off = 32; off > 0; off >>= 1) m = fmaxf(m, __shfl_xor(m, off));
    float ex = (lane < 50) ? expf(v - m) : 0.0f;
    float s = ex;
#pragma unroll
    for (int off = 32; off > 0; off >>= 1) s += __shfl_xor(s, off);
    if (lane < 50) out[(size_t)node * 50 + lane] = ex / s;
}

// ---------------------------------------------------------------------------

extern "C" void kernel_launch(void* const* d_in, const int* in_sizes, int n_in,
                              void* d_out, int out_size, void* d_ws, size_t ws_size,
                              hipStream_t stream) {
    const float* x    = (const float*)d_in[0];
    const int*   ei   = (const int*)  d_in[1];
    const float* w1   = (const float*)d_in[2];
    const float* b1   = (const float*)d_in[3];
    const float* w2   = (const float*)d_in[4];
    const float* b2   = (const float*)d_in[5];
    const float* w3   = (const float*)d_in[6];
    const float* b3   = (const float*)d_in[7];
    const float* g1w  = (const float*)d_in[8];
    const float* g1b  = (const float*)d_in[9];
    const float* g2w  = (const float*)d_in[10];
    const float* g2b  = (const float*)d_in[11];
    const float* g3w  = (const float*)d_in[12];
    const float* g3b  = (const float*)d_in[13];
    float* out = (float*)d_out;

    const int N = in_sizes[0] / 3;      // 50000
    const int E = in_sizes[1] / 2;      // 800000
    const int* src = ei;
    const int* dst = ei + E;
    const int NB = (N + 255) / 256;     // 196

    // ---- workspace arena with liveness-based region reuse ----
    char* ws = (char*)d_ws;
    size_t off = 0;
    auto alloc = [&](size_t bytes) -> char* {
        char* p = ws + off;
        off = (off + bytes + 255) & ~(size_t)255;
        return p;
    };
    int*   counts  = (int*)  alloc((size_t)N * 4);
    int*   offsets = (int*)  alloc((size_t)(N + 1) * 4);
    int*   cursor  = (int*)  alloc((size_t)N * 4);
    float* dinv    = (float*)alloc((size_t)N * 4);
    int*   bsum    = (int*)  alloc((size_t)256 * 4);
    int*   bsumx   = (int*)  alloc((size_t)256 * 4);
    int*   ssrc    = (int*)  alloc((size_t)E * 4);
    float* snorm   = (float*)alloc((size_t)E * 4);
    unsigned short* Bt1 = (unsigned short*)alloc((size_t)256 * 256 * 2);
    unsigned short* Bt2 = (unsigned short*)alloc((size_t)512 * 512 * 2);
    unsigned short* Bt3 = (unsigned short*)alloc((size_t)64 * 1024 * 2);
    unsigned short* Bt0 = (unsigned short*)alloc((size_t)128 * 128 * 2);
    char* R1 = alloc((size_t)N * 256 * 4);   // 51.2 MB
    char* R2 = alloc((size_t)N * 256 * 4);   // 51.2 MB
    char* R3 = alloc((size_t)N * 512 * 2);   // 51.2 MB (A512 fp16)
    (void)ws_size;

    // R1 phase 1: S128f16 [N,128] fp16 | A128h | A128l   phase 2: A256h|A256l
    _Float16*       S128f = (_Float16*)R1;
    unsigned short* A128h = (unsigned short*)(R1 + (size_t)N * 128 * 2);
    unsigned short* A128l = (unsigned short*)(R1 + (size_t)N * 128 * 4);
    unsigned short* A256h = (unsigned short*)R1;
    unsigned short* A256l = (unsigned short*)(R1 + (size_t)N * 256 * 2);
    // R2 phase 1: H2h|H2l [N,64] bf16   phase 2: G1f16 [N,256] fp16
    // phase 3: zbuf [N,64] fp16
    unsigned short* H2h  = (unsigned short*)R2;
    unsigned short* H2l  = (unsigned short*)(R2 + (size_t)N * 64 * 2);
    _Float16*       G1f  = (_Float16*)R2;
    _Float16*       zbuf = (_Float16*)R2;
    // R3: A512f fp16 [N,512]
    _Float16*       A512f = (_Float16*)R3;

    // ---- degree + CSR + weight prep ----
    hipMemsetAsync(counts, 0, (size_t)N * 4, stream);
    hist_kernel<<<(E + 255) / 256, 256, 0, stream>>>(dst, counts, E);
    scan1_kernel<<<NB, 256, 0, stream>>>(counts, bsum, N);
    scan2_kernel<<<1, 256, 0, stream>>>(bsum, bsumx, offsets, NB, N);
    scan3_kernel<<<NB, 256, 0, stream>>>(counts, bsumx, offsets, cursor, dinv, N);
    fill_kernel<<<(E + 255) / 256, 256, 0, stream>>>(src, dst, dinv, cursor, ssrc, snorm, E);
    prepw_kernel<<<(204800 + 255) / 256, 256, 0, stream>>>(
        g1w, g2w, g3w, w3, Bt1, Bt2, Bt3, Bt0);

    const int MB = (N + 127) / 128;     // 391 row-blocks (BM=128)
    const int MB64 = (N + 63) / 64;     // 782 row-blocks (BM=64)

    // ---- MLP: x -> h2 hi/lo (fused), h2 -> h3 fp16 table (MFMA, K=64) ----
    mlp12_kernel<<<NB, 256, 0, stream>>>(x, w1, b1, w2, b2, H2h, H2l, N);
    {   dim3 grid(1, MB);
        gemm_mfma_kernel<128, 128, 4, 2, 2, 4, 4, 3, false><<<grid, 256, 0, stream>>>(
            H2h, H2l, Bt0, b3, nullptr, (unsigned short*)S128f, nullptr, N, 64, 128);
    }

    // ---- GCN1: agg@128 (fp16 table) -> MFMA 128->256 BN=128 (fp16 out) ----
    agg_f16_kernel<128><<<((size_t)N * 16 + 255) / 256, 256, 0, stream>>>(
        S128f, offsets, ssrc, snorm, dinv, A128h, A128l, N);
    {   dim3 grid(2, MB);
        gemm_mfma_kernel<128, 128, 4, 2, 2, 4, 4, 3, false><<<grid, 256, 0, stream>>>(
            A128h, A128l, Bt1, g1b, nullptr, (unsigned short*)G1f, nullptr, N, 128, 256);
    }

    // ---- GCN2: agg@256 (fp16 table) -> MFMA 256->512 BN=128 (fp16 out) ----
    agg_f16_kernel<256><<<((size_t)N * 32 + 255) / 256, 256, 0, stream>>>(
        G1f, offsets, ssrc, snorm, dinv, A256h, A256l, N);
    {   dim3 grid(4, MB);
        gemm_mfma_kernel<128, 128, 4, 2, 2, 4, 4, 3, false><<<grid, 256, 0, stream>>>(
            A256h, A256l, Bt2, g2b, nullptr, (unsigned short*)A512f, nullptr, N, 256, 512);
    }

    // ---- GCN3: MFMA 512->64 BM=64 AF16 (fp16 out) -> fused agg + softmax ----
    {   dim3 grid(1, MB64);
        gemm_mfma_kernel<64, 64, 4, 4, 1, 1, 4, 4, true><<<grid, 256, 0, stream>>>(
            (const unsigned short*)A512f, nullptr, Bt3, nullptr,
            nullptr, (unsigned short*)zbuf, nullptr, N, 512, 64);
    }
    agg50_softmax_kernel<<<(N + 3) / 4, 256, 0, stream>>>(
        zbuf, offsets, ssrc, snorm, dinv, g3b, out, N);
}

// Round 12
// 489.566 us; speedup vs baseline: 1.1521x; 1.0003x over previous
//
#include <hip/hip_runtime.h>
#include <hip/hip_bf16.h>
#include <math.h>

// ---------------------------------------------------------------------------
// GCN part-seg pipeline.
// R12: A-operands of GCN1/GCN2 GEMMs stored as single fp16 plane (AF16
//      in-register hi/lo split, proven on GCN3) -- halves A fetch AND the
//      producing agg kernels' writes. XCD-cooperative swizzle: column blocks
//      of one row-block share b%8 (same XCD under round-robin) -> one A fetch
//      per row-block. Rest identical to R11.
// ---------------------------------------------------------------------------

typedef __attribute__((ext_vector_type(8))) short short8;     // 8 bf16
typedef __attribute__((ext_vector_type(8))) _Float16 half8;   // 8 fp16
typedef __attribute__((ext_vector_type(4))) float floatx4;    // 4 fp32

__device__ __forceinline__ unsigned short bf16h(float f) {
    unsigned int u = __float_as_uint(f);
    u += 0x7fff + ((u >> 16) & 1);          // round-to-nearest-even
    return (unsigned short)(u >> 16);
}
__device__ __forceinline__ float bf16f(unsigned short h) {
    return __uint_as_float(((unsigned int)h) << 16);
}

__device__ __forceinline__ void gld_lds16(unsigned short* lds, const unsigned short* g) {
    __builtin_amdgcn_global_load_lds(
        (const __attribute__((address_space(1))) unsigned int*)g,
        (__attribute__((address_space(3))) unsigned int*)lds, 16, 0, 0);
}

// ---------------- degree / CSR build ----------------

__global__ void hist_kernel(const int* __restrict__ dst, int* __restrict__ counts, int e) {
    int g = blockIdx.x * blockDim.x + threadIdx.x;
    if (g < e) atomicAdd(&counts[dst[g]], 1);
}

__global__ void scan1_kernel(const int* __restrict__ counts, int* __restrict__ bsum, int n) {
    __shared__ int buf[256];
    int i = blockIdx.x * 256 + threadIdx.x;
    buf[threadIdx.x] = (i < n) ? counts[i] : 0;
    __syncthreads();
    for (int off = 128; off > 0; off >>= 1) {
        if (threadIdx.x < off) buf[threadIdx.x] += buf[threadIdx.x + off];
        __syncthreads();
    }
    if (threadIdx.x == 0) bsum[blockIdx.x] = buf[0];
}

__global__ void scan2_kernel(const int* __restrict__ bsum, int* __restrict__ bsumx,
                             int* __restrict__ offsets, int nb, int n) {
    __shared__ int buf[256];
    int tid = threadIdx.x;
    int v = (tid < nb) ? bsum[tid] : 0;
    buf[tid] = v;
    __syncthreads();
    for (int off = 1; off < 256; off <<= 1) {
        int t = (tid >= off) ? buf[tid - off] : 0;
        __syncthreads();
        buf[tid] += t;
        __syncthreads();
    }
    if (tid < nb) bsumx[tid] = buf[tid] - v;       // exclusive
    if (tid == 255) offsets[n] = buf[255];          // total
}

__global__ void scan3_kernel(const int* __restrict__ counts, const int* __restrict__ bsumx,
                             int* __restrict__ offsets, int* __restrict__ cursor,
                             float* __restrict__ dinv, int n) {
    __shared__ int buf[256];
    int tid = threadIdx.x;
    int i = blockIdx.x * 256 + tid;
    int c = (i < n) ? counts[i] : 0;
    buf[tid] = c;
    __syncthreads();
    for (int off = 1; off < 256; off <<= 1) {
        int t = (tid >= off) ? buf[tid - off] : 0;
        __syncthreads();
        buf[tid] += t;
        __syncthreads();
    }
    if (i < n) {
        int excl = bsumx[blockIdx.x] + buf[tid] - c;
        offsets[i] = excl;
        cursor[i] = excl;
        dinv[i] = rsqrtf((float)c + 1.0f);
    }
}

__global__ void fill_kernel(const int* __restrict__ src, const int* __restrict__ dst,
                            const float* __restrict__ dinv, int* __restrict__ cursor,
                            int* __restrict__ ssrc, float* __restrict__ snorm, int e) {
    int g = blockIdx.x * blockDim.x + threadIdx.x;
    if (g >= e) return;
    int s = src[g], d = dst[g];
    int pos = atomicAdd(&cursor[d], 1);
    ssrc[pos]  = s;
    snorm[pos] = dinv[s] * dinv[d];
}

// ---------------- fused weight prep: W[K][N] fp32 -> Bt[N][2K] = [Bh;Bl] ----

__device__ __forceinline__ void wsplit_one(float w, unsigned short* Bt, int k, int n, int K) {
    unsigned short h = bf16h(w);
    unsigned short l = bf16h(w - bf16f(h));
    size_t base = (size_t)n * (2 * K);
    Bt[base + k]     = h;
    Bt[base + K + k] = l;
}

__global__ void prepw_kernel(const float* __restrict__ g1w, const float* __restrict__ g2w,
                             const float* __restrict__ g3w, const float* __restrict__ w3,
                             unsigned short* __restrict__ Bt1,
                             unsigned short* __restrict__ Bt2,
                             unsigned short* __restrict__ Bt3,
                             unsigned short* __restrict__ Bt0) {
    int gid = blockIdx.x * blockDim.x + threadIdx.x;
    if (gid < 32768) {                       // g1: K=128, N=256
        int k = gid >> 8, n = gid & 255;
        wsplit_one(g1w[gid], Bt1, k, n, 128);
    } else if (gid < 32768 + 131072) {       // g2: K=256, N=512
        int idx = gid - 32768;
        int k = idx >> 9, n = idx & 511;
        wsplit_one(g2w[idx], Bt2, k, n, 256);
    } else if (gid < 32768 + 131072 + 32768) { // g3 padded: K=512, N=64
        int idx = gid - 32768 - 131072;
        int k = idx >> 6, c = idx & 63;
        float w = (c < 50) ? g3w[k * 50 + c] : 0.0f;
        wsplit_one(w, Bt3, k, c, 512);
    } else if (gid < 32768 + 131072 + 32768 + 8192) { // w3: K=64, N=128
        int idx = gid - 32768 - 131072 - 32768;
        int k = idx >> 7, n = idx & 127;
        wsplit_one(w3[idx], Bt0, k, n, 64);
    }
}

// ---------------- fused MLP layers 1+2: x[N,3] -> h2 hi/lo bf16 planes ------

__global__ __launch_bounds__(256) void mlp12_kernel(
        const float* __restrict__ x,
        const float* __restrict__ w1, const float* __restrict__ b1,
        const float* __restrict__ w2, const float* __restrict__ b2,
        unsigned short* __restrict__ H2h, unsigned short* __restrict__ H2l, int n) {
    __shared__ float sw1[96], sb1[32], sw2[2048], sb2[64];
    int tid = threadIdx.x;
    if (tid < 96) sw1[tid] = w1[tid];
    if (tid < 32) sb1[tid] = b1[tid];
    if (tid < 64) sb2[tid] = b2[tid];
    for (int i = tid; i < 2048; i += 256) sw2[i] = w2[i];
    __syncthreads();

    int node = blockIdx.x * 256 + tid;
    if (node >= n) return;
    float x0 = x[node * 3 + 0], x1 = x[node * 3 + 1], x2 = x[node * 3 + 2];
    float h1[32];
#pragma unroll
    for (int j = 0; j < 32; j++)
        h1[j] = fmaxf(sb1[j] + x0 * sw1[j] + x1 * sw1[32 + j] + x2 * sw1[64 + j], 0.0f);

    float acc[64];
#pragma unroll
    for (int j = 0; j < 64; j++) acc[j] = sb2[j];
    for (int k = 0; k < 32; k++) {
        float hk = h1[k];
#pragma unroll
        for (int j4 = 0; j4 < 16; j4++) {
            float4 w = *(const float4*)&sw2[k * 64 + j4 * 4];
            acc[j4 * 4 + 0] = fmaf(hk, w.x, acc[j4 * 4 + 0]);
            acc[j4 * 4 + 1] = fmaf(hk, w.y, acc[j4 * 4 + 1]);
            acc[j4 * 4 + 2] = fmaf(hk, w.z, acc[j4 * 4 + 2]);
            acc[j4 * 4 + 3] = fmaf(hk, w.w, acc[j4 * 4 + 3]);
        }
    }
#pragma unroll
    for (int j4 = 0; j4 < 16; j4++) {
        ushort4 h4, l4;
        unsigned short* hp = (unsigned short*)&h4;
        unsigned short* lp = (unsigned short*)&l4;
#pragma unroll
        for (int t = 0; t < 4; t++) {
            float v = fmaxf(acc[j4 * 4 + t], 0.0f);
            unsigned short h = bf16h(v);
            hp[t] = h;
            lp[t] = bf16h(v - bf16f(h));
        }
        *(ushort4*)&H2h[(size_t)node * 64 + j4 * 4] = h4;
        *(ushort4*)&H2l[(size_t)node * 64 + j4 * 4] = l4;
    }
}

// ---------------- MFMA GEMM, double-bf16, 4-plane staging -------------------
// C[M,N] = (Ah+Al)[M,K] @ (Bh+Bl)[K,N]  ~=  AhBh + AhBl + AlBh.
// Bt[N][2K] = [Bh;Bl]. BK=32. Block = WAVES*64 threads, tile BM x BN.
// AF16: A is a single fp16 plane (arg Ah); hi/lo split done in registers.
// SWIZCOLS>0: 1D grid, col-blocks of one row-block share b%8 -> same XCD
// (round-robin heuristic; neutral if mapping false).
// MODE 0: Cf=relu(C+bias). MODE 1: relu(C+bias) -> Ch/Cl bf16 planes.
// MODE 2: Cf=C. MODE 3: fp16(relu(C+bias)) -> Ch. MODE 4: fp16(C) -> Ch.

template<int BM, int BN, int WAVES, int WGR, int WGC, int WRF, int WCF, int MODE,
         bool AF16, int SWIZCOLS>
__global__ __launch_bounds__(WAVES * 64) void gemm_mfma_kernel(
        const unsigned short* __restrict__ Ah, const unsigned short* __restrict__ Al,
        const unsigned short* __restrict__ Bt, const float* __restrict__ bias,
        float* __restrict__ Cf, unsigned short* __restrict__ Ch,
        unsigned short* __restrict__ Cl, int M, int K, int N) {
    static_assert(WGR * WRF * 16 == BM, "row cover");
    static_assert(WGC * WCF * 16 == BN, "col cover");
    static_assert(WGR * WGC == WAVES, "wave grid");
    constexpr int AUNITS = AF16 ? (BM / 16) : (BM / 8);
    constexpr int BUNITS = BN / 8;
    static_assert(AUNITS % WAVES == 0 && BUNITS % WAVES == 0, "staging split");
    __shared__ __align__(16) unsigned short Ash[BM * 32];
    __shared__ __align__(16) unsigned short Asl[AF16 ? 16 : BM * 32];
    __shared__ __align__(16) unsigned short Bsh[BN * 32];
    __shared__ __align__(16) unsigned short Bsl[BN * 32];

    int bm, bn;
    if (SWIZCOLS > 0) {
        constexpr int CSH = (SWIZCOLS == 4) ? 2 : 1;
        int b = blockIdx.x;
        int col = (b >> 3) & (SWIZCOLS - 1);
        int row = ((b >> (3 + CSH)) << 3) | (b & 7);
        bm = row * BM;
        bn = col * BN;
        if (bm >= M) return;             // padded row block (uniform exit)
    } else {
        bm = blockIdx.y * BM;
        bn = blockIdx.x * BN;
    }

    const int tid  = threadIdx.x;
    const int lane = tid & 63;
    const int wave = tid >> 6;
    const int K2 = 2 * K;

    const int wr0 = (wave / WGC) * (WRF * 16);
    const int wc0 = (wave % WGC) * (WCF * 16);
    const int lr   = lane & 15;
    const int quad = lane >> 4;
    const int arow = lane >> 2;          // row within 16-row group
    const int acol = (lane & 3) * 8;     // halves within 32-half row

    floatx4 acc[WRF][WCF];
#pragma unroll
    for (int i = 0; i < WRF; i++)
#pragma unroll
        for (int j = 0; j < WCF; j++) acc[i][j] = floatx4{0.f, 0.f, 0.f, 0.f};

    for (int k0 = 0; k0 < K; k0 += 32) {
        // A staging
#pragma unroll
        for (int u = 0; u < AUNITS / WAVES; u++) {
            int unit = wave + u * WAVES;
            if (AF16) {
                int grp = unit;
                int gm = bm + grp * 16 + arow;
                if (gm >= M) gm = M - 1;
                gld_lds16(&Ash[grp * 512], Ah + (size_t)gm * K + k0 + acol);
            } else {
                int grp = unit >> 1, pl = unit & 1;
                int gm = bm + grp * 16 + arow;
                if (gm >= M) gm = M - 1;     // clamp: garbage rows discarded at store
                size_t go = (size_t)gm * K + k0 + acol;
                if (pl) gld_lds16(&Asl[grp * 512], Al + go);
                else    gld_lds16(&Ash[grp * 512], Ah + go);
            }
        }
        // B staging: BN/16 col-groups x 2 planes
#pragma unroll
        for (int u = 0; u < BUNITS / WAVES; u++) {
            int unit = wave + u * WAVES;
            int grp = unit >> 1, pl = unit & 1;
            int gr = bn + grp * 16 + arow;
            size_t go = (size_t)gr * K2 + k0 + acol + (pl ? K : 0);
            if (pl) gld_lds16(&Bsl[grp * 512], Bt + go);
            else    gld_lds16(&Bsh[grp * 512], Bt + go);
        }
        __syncthreads();

        short8 ahf[WRF], alf[WRF], bhf[WCF], blf[WCF];
#pragma unroll
        for (int i = 0; i < WRF; i++) {
            int ro = (wr0 + i * 16 + lr) * 32 + quad * 8;
            if (AF16) {
                half8 av = *reinterpret_cast<const half8*>(&Ash[ro]);
#pragma unroll
                for (int t = 0; t < 8; t++) {
                    float f = (float)av[t];
                    unsigned short h = bf16h(f);
                    ahf[i][t] = (short)h;
                    alf[i][t] = (short)bf16h(f - bf16f(h));
                }
            } else {
                ahf[i] = *reinterpret_cast<const short8*>(&Ash[ro]);
                alf[i] = *reinterpret_cast<const short8*>(&Asl[ro]);
            }
        }
#pragma unroll
        for (int j = 0; j < WCF; j++) {
            int ro = (wc0 + j * 16 + lr) * 32 + quad * 8;
            bhf[j] = *reinterpret_cast<const short8*>(&Bsh[ro]);
            blf[j] = *reinterpret_cast<const short8*>(&Bsl[ro]);
        }
#pragma unroll
        for (int i = 0; i < WRF; i++)
#pragma unroll
            for (int j = 0; j < WCF; j++) {
                acc[i][j] = __builtin_amdgcn_mfma_f32_16x16x32_bf16(
                    ahf[i], bhf[j], acc[i][j], 0, 0, 0);
                acc[i][j] = __builtin_amdgcn_mfma_f32_16x16x32_bf16(
                    ahf[i], blf[j], acc[i][j], 0, 0, 0);
                acc[i][j] = __builtin_amdgcn_mfma_f32_16x16x32_bf16(
                    alf[i], bhf[j], acc[i][j], 0, 0, 0);
            }
        __syncthreads();
    }

    // epilogue: C/D layout col=lane&15, row=quad*4+reg (m89-verified)
#pragma unroll
    for (int i = 0; i < WRF; i++) {
#pragma unroll
        for (int j = 0; j < WCF; j++) {
            int gc = bn + wc0 + j * 16 + lr;
#pragma unroll
            for (int reg = 0; reg < 4; reg++) {
                int gr = bm + wr0 + i * 16 + quad * 4 + reg;
                if (gr >= M) continue;
                float v = acc[i][j][reg];
                if (MODE == 0) {
                    v = fmaxf(v + bias[gc], 0.0f);
                    Cf[(size_t)gr * N + gc] = v;
                } else if (MODE == 1) {
                    v = fmaxf(v + bias[gc], 0.0f);
                    unsigned short h = bf16h(v);
                    unsigned short l = bf16h(v - bf16f(h));
                    Ch[(size_t)gr * N + gc] = h;
                    Cl[(size_t)gr * N + gc] = l;
                } else if (MODE == 2) {
                    Cf[(size_t)gr * N + gc] = v;
                } else if (MODE == 3) {  // fp16 activation store
                    v = fmaxf(v + bias[gc], 0.0f);
                    ((_Float16*)Ch)[(size_t)gr * N + gc] = (_Float16)v;
                } else {                 // MODE 4: fp16 raw store
                    ((_Float16*)Ch)[(size_t)gr * N + gc] = (_Float16)v;
                }
            }
        }
    }
}

// ---------------- aggregation from fp16 table -> fp16 plane -----------------
// thread per (node, half8); out = fp16(AGG(table)) (GEMM AF16 A-operand).

template<int F>
__global__ void agg_f16_kernel(const _Float16* __restrict__ table,
                               const int* __restrict__ offsets,
                               const int* __restrict__ ssrc,
                               const float* __restrict__ snorm,
                               const float* __restrict__ dinv,
                               _Float16* __restrict__ Aout, int n) {
    constexpr int F8 = F / 8;
    int gid = blockIdx.x * blockDim.x + threadIdx.x;
    if (gid >= n * F8) return;
    int node = gid / F8;                 // F8 pow2 -> shift
    int c8 = (gid - node * F8) * 8;

    float acc[8];
#pragma unroll
    for (int i = 0; i < 8; i++) acc[i] = 0.0f;

    int beg = offsets[node], end = offsets[node + 1];
    for (int e = beg; e < end; ++e) {
        int s = ssrc[e];
        float w = snorm[e];
        half8 r = *reinterpret_cast<const half8*>(table + (size_t)s * F + c8);
#pragma unroll
        for (int i = 0; i < 8; i++) acc[i] = fmaf((float)r[i], w, acc[i]);
    }
    float dv = dinv[node];
    float sw = dv * dv;
    half8 r = *reinterpret_cast<const half8*>(table + (size_t)node * F + c8);
#pragma unroll
    for (int i = 0; i < 8; i++) acc[i] = fmaf((float)r[i], sw, acc[i]);

    half8 o;
#pragma unroll
    for (int i = 0; i < 8; i++) o[i] = (_Float16)acc[i];
    *reinterpret_cast<half8*>(&Aout[(size_t)node * F + c8]) = o;
}

// ---------------- fused final aggregation + softmax: one wave per node ------
// z[N,64] fp16 (cols 50..63 zero); out[N,50] = softmax(AGG(z)+bias).
// Edge loop unrolled 4x (L2-latency-bound regime).

__global__ void agg50_softmax_kernel(const _Float16* __restrict__ z,
                                     const int* __restrict__ offsets,
                                     const int* __restrict__ ssrc,
                                     const float* __restrict__ snorm,
                                     const float* __restrict__ dinv,
                                     const float* __restrict__ bias,
                                     float* __restrict__ out, int n) {
    int node = blockIdx.x * 4 + (threadIdx.x >> 6);
    int lane = threadIdx.x & 63;
    if (node >= n) return;

    float a0 = 0.f, a1 = 0.f, a2 = 0.f, a3 = 0.f;
    int beg = offsets[node], end = offsets[node + 1];
    int e = beg;
    for (; e + 4 <= end; e += 4) {
        int s0 = ssrc[e + 0], s1 = ssrc[e + 1], s2 = ssrc[e + 2], s3 = ssrc[e + 3];
        float w0 = snorm[e + 0], w1 = snorm[e + 1];
        float w2 = snorm[e + 2], w3 = snorm[e + 3];
        float r0 = (float)z[(size_t)s0 * 64 + lane];
        float r1 = (float)z[(size_t)s1 * 64 + lane];
        float r2 = (float)z[(size_t)s2 * 64 + lane];
        float r3 = (float)z[(size_t)s3 * 64 + lane];
        a0 = fmaf(r0, w0, a0);
        a1 = fmaf(r1, w1, a1);
        a2 = fmaf(r2, w2, a2);
        a3 = fmaf(r3, w3, a3);
    }
    for (; e < end; ++e)
        a0 = fmaf((float)z[(size_t)ssrc[e] * 64 + lane], snorm[e], a0);

    float dv = dinv[node];
    float a = fmaf((float)z[(size_t)node * 64 + lane], dv * dv,
                   (a0 + a1) + (a2 + a3));

    float v = (lane < 50) ? a + bias[lane] : -INFINITY;
    float m = v;
#pragma unroll
    for (int off = 32; off > 0; off >>= 1) m = fmaxf(m, __shfl_xor(m, off));
    float ex = (lane < 50) ? expf(v - m) : 0.0f;
    float s = ex;
#pragma unroll
    for (int off = 32; off > 0; off >>= 1) s += __shfl_xor(s, off);
    if (lane < 50) out[(size_t)node * 50 + lane] = ex / s;
}

// ---------------------------------------------------------------------------

extern "C" void kernel_launch(void* const* d_in, const int* in_sizes, int n_in,
                              void* d_out, int out_size, void* d_ws, size_t ws_size,
                              hipStream_t stream) {
    const float* x    = (const float*)d_in[0];
    const int*   ei   = (const int*)  d_in[1];
    const float* w1   = (const float*)d_in[2];
    const float* b1   = (const float*)d_in[3];
    const float* w2   = (const float*)d_in[4];
    const float* b2   = (const float*)d_in[5];
    const float* w3   = (const float*)d_in[6];
    const float* b3   = (const float*)d_in[7];
    const float* g1w  = (const float*)d_in[8];
    const float* g1b  = (const float*)d_in[9];
    const float* g2w  = (const float*)d_in[10];
    const float* g2b  = (const float*)d_in[11];
    const float* g3w  = (const float*)d_in[12];
    const float* g3b  = (const float*)d_in[13];
    float* out = (float*)d_out;

    const int N = in_sizes[0] / 3;      // 50000
    const int E = in_sizes[1] / 2;      // 800000
    const int* src = ei;
    const int* dst = ei + E;
    const int NB = (N + 255) / 256;     // 196

    // ---- workspace arena with liveness-based region reuse ----
    char* ws = (char*)d_ws;
    size_t off = 0;
    auto alloc = [&](size_t bytes) -> char* {
        char* p = ws + off;
        off = (off + bytes + 255) & ~(size_t)255;
        return p;
    };
    int*   counts  = (int*)  alloc((size_t)N * 4);
    int*   offsets = (int*)  alloc((size_t)(N + 1) * 4);
    int*   cursor  = (int*)  alloc((size_t)N * 4);
    float* dinv    = (float*)alloc((size_t)N * 4);
    int*   bsum    = (int*)  alloc((size_t)256 * 4);
    int*   bsumx   = (int*)  alloc((size_t)256 * 4);
    int*   ssrc    = (int*)  alloc((size_t)E * 4);
    float* snorm   = (float*)alloc((size_t)E * 4);
    unsigned short* Bt1 = (unsigned short*)alloc((size_t)256 * 256 * 2);
    unsigned short* Bt2 = (unsigned short*)alloc((size_t)512 * 512 * 2);
    unsigned short* Bt3 = (unsigned short*)alloc((size_t)64 * 1024 * 2);
    unsigned short* Bt0 = (unsigned short*)alloc((size_t)128 * 128 * 2);
    char* R1 = alloc((size_t)N * 256 * 4);   // 51.2 MB
    char* R2 = alloc((size_t)N * 256 * 4);   // 51.2 MB
    char* R3 = alloc((size_t)N * 512 * 2);   // 51.2 MB (A512 fp16)
    (void)ws_size;

    // R1 phase 1: S128f [N,128] fp16 | A128f [N,128] fp16   phase 2: A256f
    _Float16*       S128f = (_Float16*)R1;
    _Float16*       A128f = (_Float16*)(R1 + (size_t)N * 128 * 2);
    _Float16*       A256f = (_Float16*)R1;
    // R2 phase 1: H2h|H2l [N,64] bf16   phase 2: G1f16 [N,256] fp16
    // phase 3: zbuf [N,64] fp16
    unsigned short* H2h  = (unsigned short*)R2;
    unsigned short* H2l  = (unsigned short*)(R2 + (size_t)N * 64 * 2);
    _Float16*       G1f  = (_Float16*)R2;
    _Float16*       zbuf = (_Float16*)R2;
    // R3: A512f fp16 [N,512]
    _Float16*       A512f = (_Float16*)R3;

    // ---- degree + CSR + weight prep ----
    hipMemsetAsync(counts, 0, (size_t)N * 4, stream);
    hist_kernel<<<(E + 255) / 256, 256, 0, stream>>>(dst, counts, E);
    scan1_kernel<<<NB, 256, 0, stream>>>(counts, bsum, N);
    scan2_kernel<<<1, 256, 0, stream>>>(bsum, bsumx, offsets, NB, N);
    scan3_kernel<<<NB, 256, 0, stream>>>(counts, bsumx, offsets, cursor, dinv, N);
    fill_kernel<<<(E + 255) / 256, 256, 0, stream>>>(src, dst, dinv, cursor, ssrc, snorm, E);
    prepw_kernel<<<(204800 + 255) / 256, 256, 0, stream>>>(
        g1w, g2w, g3w, w3, Bt1, Bt2, Bt3, Bt0);

    const int MB = (N + 127) / 128;     // 391 row-blocks (BM=128)
    const int MB8 = (MB + 7) & ~7;      // 392 (pad to 8 for swizzle)
    const int MB64 = (N + 63) / 64;     // 782 row-blocks (BM=64)

    // ---- MLP: x -> h2 hi/lo (fused), h2 -> h3 fp16 table (MFMA, K=64) ----
    mlp12_kernel<<<NB, 256, 0, stream>>>(x, w1, b1, w2, b2, H2h, H2l, N);
    {   dim3 grid(1, MB);
        gemm_mfma_kernel<128, 128, 4, 2, 2, 4, 4, 3, false, 0><<<grid, 256, 0, stream>>>(
            H2h, H2l, Bt0, b3, nullptr, (unsigned short*)S128f, nullptr, N, 64, 128);
    }

    // ---- GCN1: agg@128 -> fp16 plane -> MFMA 128->256 AF16 swiz2 ----
    agg_f16_kernel<128><<<((size_t)N * 16 + 255) / 256, 256, 0, stream>>>(
        S128f, offsets, ssrc, snorm, dinv, A128f, N);
    {
        gemm_mfma_kernel<128, 128, 4, 2, 2, 4, 4, 3, true, 2><<<2 * MB8, 256, 0, stream>>>(
            (const unsigned short*)A128f, nullptr, Bt1, g1b,
            nullptr, (unsigned short*)G1f, nullptr, N, 128, 256);
    }

    // ---- GCN2: agg@256 -> fp16 plane -> MFMA 256->512 AF16 swiz4 ----
    agg_f16_kernel<256><<<((size_t)N * 32 + 255) / 256, 256, 0, stream>>>(
        G1f, offsets, ssrc, snorm, dinv, A256f, N);
    {
        gemm_mfma_kernel<128, 128, 4, 2, 2, 4, 4, 3, true, 4><<<4 * MB8, 256, 0, stream>>>(
            (const unsigned short*)A256f, nullptr, Bt2, g2b,
            nullptr, (unsigned short*)A512f, nullptr, N, 256, 512);
    }

    // ---- GCN3: MFMA 512->64 BM=64 AF16 (fp16 out) -> fused agg + softmax ----
    {   dim3 grid(1, MB64);
        gemm_mfma_kernel<64, 64, 4, 4, 1, 1, 4, 4, true, 0><<<grid, 256, 0, stream>>>(
            (const unsigned short*)A512f, nullptr, Bt3, nullptr,
            nullptr, (unsigned short*)zbuf, nullptr, N, 512, 64);
    }
    agg50_softmax_kernel<<<(N + 3) / 4, 256, 0, stream>>>(
        zbuf, offsets, ssrc, snorm, dinv, g3b, out, N);
}

// Round 13
// 453.854 us; speedup vs baseline: 1.2427x; 1.0787x over previous
//
#include <hip/hip_runtime.h>
#include <hip/hip_bf16.h>
#include <math.h>

// ---------------------------------------------------------------------------
// GCN part-seg pipeline.
// R13: MLP3/GCN1/GCN2 GEMMs use native f16 MFMA (fp16 A and fp16 B, no
//      double-bf16 emulation): 1/3 MFMA work, half staging, no VALU split.
//      Rationale: activations already fp16 (2^-11, proven harmless over 5
//      insertions); fp16 weights add error of the same order. GCN3 (logit
//      layer) keeps bf16 emulation. Swizzle kept (R12: FETCH 106->16 MB).
// ---------------------------------------------------------------------------

typedef __attribute__((ext_vector_type(8))) short short8;     // 8 bf16
typedef __attribute__((ext_vector_type(8))) _Float16 half8;   // 8 fp16
typedef __attribute__((ext_vector_type(4))) float floatx4;    // 4 fp32

__device__ __forceinline__ unsigned short bf16h(float f) {
    unsigned int u = __float_as_uint(f);
    u += 0x7fff + ((u >> 16) & 1);          // round-to-nearest-even
    return (unsigned short)(u >> 16);
}
__device__ __forceinline__ float bf16f(unsigned short h) {
    return __uint_as_float(((unsigned int)h) << 16);
}

__device__ __forceinline__ void gld_lds16(unsigned short* lds, const unsigned short* g) {
    __builtin_amdgcn_global_load_lds(
        (const __attribute__((address_space(1))) unsigned int*)g,
        (__attribute__((address_space(3))) unsigned int*)lds, 16, 0, 0);
}

// ---------------- degree / CSR build ----------------

__global__ void hist_kernel(const int* __restrict__ dst, int* __restrict__ counts, int e) {
    int g = blockIdx.x * blockDim.x + threadIdx.x;
    if (g < e) atomicAdd(&counts[dst[g]], 1);
}

__global__ void scan1_kernel(const int* __restrict__ counts, int* __restrict__ bsum, int n) {
    __shared__ int buf[256];
    int i = blockIdx.x * 256 + threadIdx.x;
    buf[threadIdx.x] = (i < n) ? counts[i] : 0;
    __syncthreads();
    for (int off = 128; off > 0; off >>= 1) {
        if (threadIdx.x < off) buf[threadIdx.x] += buf[threadIdx.x + off];
        __syncthreads();
    }
    if (threadIdx.x == 0) bsum[blockIdx.x] = buf[0];
}

__global__ void scan2_kernel(const int* __restrict__ bsum, int* __restrict__ bsumx,
                             int* __restrict__ offsets, int nb, int n) {
    __shared__ int buf[256];
    int tid = threadIdx.x;
    int v = (tid < nb) ? bsum[tid] : 0;
    buf[tid] = v;
    __syncthreads();
    for (int off = 1; off < 256; off <<= 1) {
        int t = (tid >= off) ? buf[tid - off] : 0;
        __syncthreads();
        buf[tid] += t;
        __syncthreads();
    }
    if (tid < nb) bsumx[tid] = buf[tid] - v;       // exclusive
    if (tid == 255) offsets[n] = buf[255];          // total
}

__global__ void scan3_kernel(const int* __restrict__ counts, const int* __restrict__ bsumx,
                             int* __restrict__ offsets, int* __restrict__ cursor,
                             float* __restrict__ dinv, int n) {
    __shared__ int buf[256];
    int tid = threadIdx.x;
    int i = blockIdx.x * 256 + tid;
    int c = (i < n) ? counts[i] : 0;
    buf[tid] = c;
    __syncthreads();
    for (int off = 1; off < 256; off <<= 1) {
        int t = (tid >= off) ? buf[tid - off] : 0;
        __syncthreads();
        buf[tid] += t;
        __syncthreads();
    }
    if (i < n) {
        int excl = bsumx[blockIdx.x] + buf[tid] - c;
        offsets[i] = excl;
        cursor[i] = excl;
        dinv[i] = rsqrtf((float)c + 1.0f);
    }
}

__global__ void fill_kernel(const int* __restrict__ src, const int* __restrict__ dst,
                            const float* __restrict__ dinv, int* __restrict__ cursor,
                            int* __restrict__ ssrc, float* __restrict__ snorm, int e) {
    int g = blockIdx.x * blockDim.x + threadIdx.x;
    if (g >= e) return;
    int s = src[g], d = dst[g];
    int pos = atomicAdd(&cursor[d], 1);
    ssrc[pos]  = s;
    snorm[pos] = dinv[s] * dinv[d];
}

// ---------------- fused weight prep ----------------
// f16 GEMMs: W[K][N] fp32 -> Btf[N][K] fp16 (transposed).
// GCN3 (emulated): g3w padded -> Bt3[N][2K] bf16 = [Bh;Bl].

__global__ void prepw_kernel(const float* __restrict__ g1w, const float* __restrict__ g2w,
                             const float* __restrict__ g3w, const float* __restrict__ w3,
                             _Float16* __restrict__ Bt1f,
                             _Float16* __restrict__ Bt2f,
                             unsigned short* __restrict__ Bt3,
                             _Float16* __restrict__ Bt0f) {
    int gid = blockIdx.x * blockDim.x + threadIdx.x;
    if (gid < 32768) {                       // g1: K=128, N=256
        int k = gid >> 8, n = gid & 255;
        Bt1f[(size_t)n * 128 + k] = (_Float16)g1w[gid];
    } else if (gid < 32768 + 131072) {       // g2: K=256, N=512
        int idx = gid - 32768;
        int k = idx >> 9, n = idx & 511;
        Bt2f[(size_t)n * 256 + k] = (_Float16)g2w[idx];
    } else if (gid < 32768 + 131072 + 32768) { // g3 padded: K=512, N=64 (bf16 hi/lo)
        int idx = gid - 32768 - 131072;
        int k = idx >> 6, c = idx & 63;
        float w = (c < 50) ? g3w[k * 50 + c] : 0.0f;
        unsigned short h = bf16h(w);
        unsigned short l = bf16h(w - bf16f(h));
        size_t base = (size_t)c * 1024;
        Bt3[base + k]       = h;
        Bt3[base + 512 + k] = l;
    } else if (gid < 32768 + 131072 + 32768 + 8192) { // w3: K=64, N=128
        int idx = gid - 32768 - 131072 - 32768;
        int k = idx >> 7, n = idx & 127;
        Bt0f[(size_t)n * 64 + k] = (_Float16)w3[idx];
    }
}

// ---------------- fused MLP layers 1+2: x[N,3] -> h2 fp16 [N,64] ------------

__global__ __launch_bounds__(256) void mlp12_kernel(
        const float* __restrict__ x,
        const float* __restrict__ w1, const float* __restrict__ b1,
        const float* __restrict__ w2, const float* __restrict__ b2,
        _Float16* __restrict__ H2f, int n) {
    __shared__ float sw1[96], sb1[32], sw2[2048], sb2[64];
    int tid = threadIdx.x;
    if (tid < 96) sw1[tid] = w1[tid];
    if (tid < 32) sb1[tid] = b1[tid];
    if (tid < 64) sb2[tid] = b2[tid];
    for (int i = tid; i < 2048; i += 256) sw2[i] = w2[i];
    __syncthreads();

    int node = blockIdx.x * 256 + tid;
    if (node >= n) return;
    float x0 = x[node * 3 + 0], x1 = x[node * 3 + 1], x2 = x[node * 3 + 2];
    float h1[32];
#pragma unroll
    for (int j = 0; j < 32; j++)
        h1[j] = fmaxf(sb1[j] + x0 * sw1[j] + x1 * sw1[32 + j] + x2 * sw1[64 + j], 0.0f);

    float acc[64];
#pragma unroll
    for (int j = 0; j < 64; j++) acc[j] = sb2[j];
    for (int k = 0; k < 32; k++) {
        float hk = h1[k];
#pragma unroll
        for (int j4 = 0; j4 < 16; j4++) {
            float4 w = *(const float4*)&sw2[k * 64 + j4 * 4];
            acc[j4 * 4 + 0] = fmaf(hk, w.x, acc[j4 * 4 + 0]);
            acc[j4 * 4 + 1] = fmaf(hk, w.y, acc[j4 * 4 + 1]);
            acc[j4 * 4 + 2] = fmaf(hk, w.z, acc[j4 * 4 + 2]);
            acc[j4 * 4 + 3] = fmaf(hk, w.w, acc[j4 * 4 + 3]);
        }
    }
#pragma unroll
    for (int j8 = 0; j8 < 8; j8++) {
        half8 o;
#pragma unroll
        for (int t = 0; t < 8; t++)
            o[t] = (_Float16)fmaxf(acc[j8 * 8 + t], 0.0f);
        *reinterpret_cast<half8*>(&H2f[(size_t)node * 64 + j8 * 8]) = o;
    }
}

// ---------------- native f16 MFMA GEMM --------------------------------------
// C[M,N] = A[M,K](fp16) @ B[K,N](fp16 as Btf[N][K]); fp32 accumulate.
// out = fp16(relu(C+bias)). SWIZCOLS>0: col blocks of a row-block share b%8.

template<int BM, int BN, int WAVES, int WGR, int WGC, int WRF, int WCF, int SWIZCOLS>
__global__ __launch_bounds__(WAVES * 64) void gemm_f16_kernel(
        const _Float16* __restrict__ A, const _Float16* __restrict__ Btf,
        const float* __restrict__ bias, _Float16* __restrict__ C,
        int M, int K, int N) {
    static_assert(WGR * WRF * 16 == BM, "row cover");
    static_assert(WGC * WCF * 16 == BN, "col cover");
    static_assert(WGR * WGC == WAVES, "wave grid");
    constexpr int AUNITS = BM / 16, BUNITS = BN / 16;
    static_assert(AUNITS % WAVES == 0 && BUNITS % WAVES == 0, "staging split");
    __shared__ __align__(16) unsigned short Ash[BM * 32];
    __shared__ __align__(16) unsigned short Bsh[BN * 32];

    int bm, bn;
    if (SWIZCOLS > 0) {
        constexpr int CSH = (SWIZCOLS == 4) ? 2 : 1;
        int b = blockIdx.x;
        int col = (b >> 3) & (SWIZCOLS - 1);
        int row = ((b >> (3 + CSH)) << 3) | (b & 7);
        bm = row * BM;
        bn = col * BN;
        if (bm >= M) return;             // padded row block (uniform exit)
    } else {
        bm = blockIdx.y * BM;
        bn = blockIdx.x * BN;
    }

    const int tid  = threadIdx.x;
    const int lane = tid & 63;
    const int wave = tid >> 6;
    const int wr0 = (wave / WGC) * (WRF * 16);
    const int wc0 = (wave % WGC) * (WCF * 16);
    const int lr   = lane & 15;
    const int quad = lane >> 4;
    const int arow = lane >> 2;          // row within 16-row group
    const int acol = (lane & 3) * 8;     // halves within 32-half row

    floatx4 acc[WRF][WCF];
#pragma unroll
    for (int i = 0; i < WRF; i++)
#pragma unroll
        for (int j = 0; j < WCF; j++) acc[i][j] = floatx4{0.f, 0.f, 0.f, 0.f};

    for (int k0 = 0; k0 < K; k0 += 32) {
#pragma unroll
        for (int u = 0; u < AUNITS / WAVES; u++) {
            int grp = wave + u * WAVES;
            int gm = bm + grp * 16 + arow;
            if (gm >= M) gm = M - 1;     // clamp: garbage rows discarded at store
            gld_lds16(&Ash[grp * 512],
                      (const unsigned short*)(A + (size_t)gm * K + k0 + acol));
        }
#pragma unroll
        for (int u = 0; u < BUNITS / WAVES; u++) {
            int grp = wave + u * WAVES;
            int gr = bn + grp * 16 + arow;
            gld_lds16(&Bsh[grp * 512],
                      (const unsigned short*)(Btf + (size_t)gr * K + k0 + acol));
        }
        __syncthreads();

        half8 af[WRF], bf[WCF];
#pragma unroll
        for (int i = 0; i < WRF; i++)
            af[i] = *reinterpret_cast<const half8*>(
                &Ash[(wr0 + i * 16 + lr) * 32 + quad * 8]);
#pragma unroll
        for (int j = 0; j < WCF; j++)
            bf[j] = *reinterpret_cast<const half8*>(
                &Bsh[(wc0 + j * 16 + lr) * 32 + quad * 8]);
#pragma unroll
        for (int i = 0; i < WRF; i++)
#pragma unroll
            for (int j = 0; j < WCF; j++)
                acc[i][j] = __builtin_amdgcn_mfma_f32_16x16x32_f16(
                    af[i], bf[j], acc[i][j], 0, 0, 0);
        __syncthreads();
    }

    // epilogue: C/D layout col=lane&15, row=quad*4+reg (m89-verified)
#pragma unroll
    for (int i = 0; i < WRF; i++) {
#pragma unroll
        for (int j = 0; j < WCF; j++) {
            int gc = bn + wc0 + j * 16 + lr;
#pragma unroll
            for (int reg = 0; reg < 4; reg++) {
                int gr = bm + wr0 + i * 16 + quad * 4 + reg;
                if (gr >= M) continue;
                float v = fmaxf(acc[i][j][reg] + bias[gc], 0.0f);
                C[(size_t)gr * N + gc] = (_Float16)v;
            }
        }
    }
}

// ---------------- emulated GEMM for GCN3 (logit layer) ----------------------
// A fp16 plane (in-register bf16 hi/lo split), B = Bt[N][2K] bf16 [Bh;Bl].
// out = fp16(C) raw (no bias/relu).

template<int BM, int BN, int WAVES, int WGR, int WGC, int WRF, int WCF>
__global__ __launch_bounds__(WAVES * 64) void gemm_emul_kernel(
        const _Float16* __restrict__ Af, const unsigned short* __restrict__ Bt,
        _Float16* __restrict__ C, int M, int K, int N) {
    static_assert(WGR * WRF * 16 == BM, "row cover");
    static_assert(WGC * WCF * 16 == BN, "col cover");
    static_assert(WGR * WGC == WAVES, "wave grid");
    constexpr int AUNITS = BM / 16, BUNITS = BN / 8;
    static_assert(AUNITS % WAVES == 0 && BUNITS % WAVES == 0, "staging split");
    __shared__ __align__(16) unsigned short Ash[BM * 32];
    __shared__ __align__(16) unsigned short Bsh[BN * 32];
    __shared__ __align__(16) unsigned short Bsl[BN * 32];

    const int bm = blockIdx.y * BM;
    const int bn = blockIdx.x * BN;
    const int tid  = threadIdx.x;
    const int lane = tid & 63;
    const int wave = tid >> 6;
    const int K2 = 2 * K;
    const int wr0 = (wave / WGC) * (WRF * 16);
    const int wc0 = (wave % WGC) * (WCF * 16);
    const int lr   = lane & 15;
    const int quad = lane >> 4;
    const int arow = lane >> 2;
    const int acol = (lane & 3) * 8;

    floatx4 acc[WRF][WCF];
#pragma unroll
    for (int i = 0; i < WRF; i++)
#pragma unroll
        for (int j = 0; j < WCF; j++) acc[i][j] = floatx4{0.f, 0.f, 0.f, 0.f};

    for (int k0 = 0; k0 < K; k0 += 32) {
#pragma unroll
        for (int u = 0; u < AUNITS / WAVES; u++) {
            int grp = wave + u * WAVES;
            int gm = bm + grp * 16 + arow;
            if (gm >= M) gm = M - 1;
            gld_lds16(&Ash[grp * 512],
                      (const unsigned short*)(Af + (size_t)gm * K + k0 + acol));
        }
#pragma unroll
        for (int u = 0; u < BUNITS / WAVES; u++) {
            int unit = wave + u * WAVES;
            int grp = unit >> 1, pl = unit & 1;
            int gr = bn + grp * 16 + arow;
            size_t go = (size_t)gr * K2 + k0 + acol + (pl ? K : 0);
            if (pl) gld_lds16(&Bsl[grp * 512], Bt + go);
            else    gld_lds16(&Bsh[grp * 512], Bt + go);
        }
        __syncthreads();

        short8 ahf[WRF], alf[WRF], bhf[WCF], blf[WCF];
#pragma unroll
        for (int i = 0; i < WRF; i++) {
            half8 av = *reinterpret_cast<const half8*>(
                &Ash[(wr0 + i * 16 + lr) * 32 + quad * 8]);
#pragma unroll
            for (int t = 0; t < 8; t++) {
                float f = (float)av[t];
                unsigned short h = bf16h(f);
                ahf[i][t] = (short)h;
                alf[i][t] = (short)bf16h(f - bf16f(h));
            }
        }
#pragma unroll
        for (int j = 0; j < WCF; j++) {
            int ro = (wc0 + j * 16 + lr) * 32 + quad * 8;
            bhf[j] = *reinterpret_cast<const short8*>(&Bsh[ro]);
            blf[j] = *reinterpret_cast<const short8*>(&Bsl[ro]);
        }
#pragma unroll
        for (int i = 0; i < WRF; i++)
#pragma unroll
            for (int j = 0; j < WCF; j++) {
                acc[i][j] = __builtin_amdgcn_mfma_f32_16x16x32_bf16(
                    ahf[i], bhf[j], acc[i][j], 0, 0, 0);
                acc[i][j] = __builtin_amdgcn_mfma_f32_16x16x32_bf16(
                    ahf[i], blf[j], acc[i][j], 0, 0, 0);
                acc[i][j] = __builtin_amdgcn_mfma_f32_16x16x32_bf16(
                    alf[i], bhf[j], acc[i][j], 0, 0, 0);
            }
        __syncthreads();
    }

#pragma unroll
    for (int i = 0; i < WRF; i++) {
#pragma unroll
        for (int j = 0; j < WCF; j++) {
            int gc = bn + wc0 + j * 16 + lr;
#pragma unroll
            for (int reg = 0; reg < 4; reg++) {
                int gr = bm + wr0 + i * 16 + quad * 4 + reg;
                if (gr >= M) continue;
                C[(size_t)gr * N + gc] = (_Float16)acc[i][j][reg];
            }
        }
    }
}

// ---------------- aggregation from fp16 table -> fp16 plane -----------------

template<int F>
__global__ void agg_f16_kernel(const _Float16* __restrict__ table,
                               const int* __restrict__ offsets,
                               const int* __restrict__ ssrc,
                               const float* __restrict__ snorm,
                               const float* __restrict__ dinv,
                               _Float16* __restrict__ Aout, int n) {
    constexpr int F8 = F / 8;
    int gid = blockIdx.x * blockDim.x + threadIdx.x;
    if (gid >= n * F8) return;
    int node = gid / F8;                 // F8 pow2 -> shift
    int c8 = (gid - node * F8) * 8;

    float acc[8];
#pragma unroll
    for (int i = 0; i < 8; i++) acc[i] = 0.0f;

    int beg = offsets[node], end = offsets[node + 1];
    for (int e = beg; e < end; ++e) {
        int s = ssrc[e];
        float w = snorm[e];
        half8 r = *reinterpret_cast<const half8*>(table + (size_t)s * F + c8);
#pragma unroll
        for (int i = 0; i < 8; i++) acc[i] = fmaf((float)r[i], w, acc[i]);
    }
    float dv = dinv[node];
    float sw = dv * dv;
    half8 r = *reinterpret_cast<const half8*>(table + (size_t)node * F + c8);
#pragma unroll
    for (int i = 0; i < 8; i++) acc[i] = fmaf((float)r[i], sw, acc[i]);

    half8 o;
#pragma unroll
    for (int i = 0; i < 8; i++) o[i] = (_Float16)acc[i];
    *reinterpret_cast<half8*>(&Aout[(size_t)node * F + c8]) = o;
}

// ---------------- fused final aggregation + softmax: one wave per node ------
// z[N,64] fp16 (cols 50..63 zero); out[N,50] = softmax(AGG(z)+bias).
// Edge loop unrolled 4x (L2-latency-bound regime).

__global__ void agg50_softmax_kernel(const _Float16* __restrict__ z,
                                     const int* __restrict__ offsets,
                                     const int* __restrict__ ssrc,
                                     const float* __restrict__ snorm,
                                     const float* __restrict__ dinv,
                                     const float* __restrict__ bias,
                                     float* __restrict__ out, int n) {
    int node = blockIdx.x * 4 + (threadIdx.x >> 6);
    int lane = threadIdx.x & 63;
    if (node >= n) return;

    float a0 = 0.f, a1 = 0.f, a2 = 0.f, a3 = 0.f;
    int beg = offsets[node], end = offsets[node + 1];
    int e = beg;
    for (; e + 4 <= end; e += 4) {
        int s0 = ssrc[e + 0], s1 = ssrc[e + 1], s2 = ssrc[e + 2], s3 = ssrc[e + 3];
        float w0 = snorm[e + 0], w1 = snorm[e + 1];
        float w2 = snorm[e + 2], w3 = snorm[e + 3];
        float r0 = (float)z[(size_t)s0 * 64 + lane];
        float r1 = (float)z[(size_t)s1 * 64 + lane];
        float r2 = (float)z[(size_t)s2 * 64 + lane];
        float r3 = (float)z[(size_t)s3 * 64 + lane];
        a0 = fmaf(r0, w0, a0);
        a1 = fmaf(r1, w1, a1);
        a2 = fmaf(r2, w2, a2);
        a3 = fmaf(r3, w3, a3);
    }
    for (; e < end; ++e)
        a0 = fmaf((float)z[(size_t)ssrc[e] * 64 + lane], snorm[e], a0);

    float dv = dinv[node];
    float a = fmaf((float)z[(size_t)node * 64 + lane], dv * dv,
                   (a0 + a1) + (a2 + a3));

    float v = (lane < 50) ? a + bias[lane] : -INFINITY;
    float m = v;
#pragma unroll
    for (int off = 32; off > 0; off >>= 1) m = fmaxf(m, __shfl_xor(m, off));
    float ex = (lane < 50) ? expf(v - m) : 0.0f;
    float s = ex;
#pragma unroll
    for (int off = 32; off > 0; off >>= 1) s += __shfl_xor(s, off);
    if (lane < 50) out[(size_t)node * 50 + lane] = ex / s;
}

// ---------------------------------------------------------------------------

extern "C" void kernel_launch(void* const* d_in, const int* in_sizes, int n_in,
                              void* d_out, int out_size, void* d_ws, size_t ws_size,
                              hipStream_t stream) {
    const float* x    = (const float*)d_in[0];
    const int*   ei   = (const int*)  d_in[1];
    const float* w1   = (const float*)d_in[2];
    const float* b1   = (const float*)d_in[3];
    const float* w2   = (const float*)d_in[4];
    const float* b2   = (const float*)d_in[5];
    const float* w3   = (const float*)d_in[6];
    const float* b3   = (const float*)d_in[7];
    const float* g1w  = (const float*)d_in[8];
    const float* g1b  = (const float*)d_in[9];
    const float* g2w  = (const float*)d_in[10];
    const float* g2b  = (const float*)d_in[11];
    const float* g3w  = (const float*)d_in[12];
    const float* g3b  = (const float*)d_in[13];
    float* out = (float*)d_out;

    const int N = in_sizes[0] / 3;      // 50000
    const int E = in_sizes[1] / 2;      // 800000
    const int* src = ei;
    const int* dst = ei + E;
    const int NB = (N + 255) / 256;     // 196

    // ---- workspace arena with liveness-based region reuse ----
    char* ws = (char*)d_ws;
    size_t off = 0;
    auto alloc = [&](size_t bytes) -> char* {
        char* p = ws + off;
        off = (off + bytes + 255) & ~(size_t)255;
        return p;
    };
    int*   counts  = (int*)  alloc((size_t)N * 4);
    int*   offsets = (int*)  alloc((size_t)(N + 1) * 4);
    int*   cursor  = (int*)  alloc((size_t)N * 4);
    float* dinv    = (float*)alloc((size_t)N * 4);
    int*   bsum    = (int*)  alloc((size_t)256 * 4);
    int*   bsumx   = (int*)  alloc((size_t)256 * 4);
    int*   ssrc    = (int*)  alloc((size_t)E * 4);
    float* snorm   = (float*)alloc((size_t)E * 4);
    _Float16* Bt1f = (_Float16*)alloc((size_t)256 * 128 * 2);
    _Float16* Bt2f = (_Float16*)alloc((size_t)512 * 256 * 2);
    unsigned short* Bt3 = (unsigned short*)alloc((size_t)64 * 1024 * 2);
    _Float16* Bt0f = (_Float16*)alloc((size_t)128 * 64 * 2);
    char* R1 = alloc((size_t)N * 256 * 4);   // 51.2 MB
    char* R2 = alloc((size_t)N * 256 * 4);   // 51.2 MB
    char* R3 = alloc((size_t)N * 512 * 2);   // 51.2 MB (A512 fp16)
    (void)ws_size;

    // R1 phase 1: S128f [N,128] fp16 | A128f [N,128] fp16   phase 2: A256f
    _Float16*       S128f = (_Float16*)R1;
    _Float16*       A128f = (_Float16*)(R1 + (size_t)N * 128 * 2);
    _Float16*       A256f = (_Float16*)R1;
    // R2 phase 1: H2f [N,64] fp16   phase 2: G1f [N,256] fp16   phase 3: zbuf
    _Float16*       H2f  = (_Float16*)R2;
    _Float16*       G1f  = (_Float16*)R2;
    _Float16*       zbuf = (_Float16*)R2;
    // R3: A512f fp16 [N,512]
    _Float16*       A512f = (_Float16*)R3;

    // ---- degree + CSR + weight prep ----
    hipMemsetAsync(counts, 0, (size_t)N * 4, stream);
    hist_kernel<<<(E + 255) / 256, 256, 0, stream>>>(dst, counts, E);
    scan1_kernel<<<NB, 256, 0, stream>>>(counts, bsum, N);
    scan2_kernel<<<1, 256, 0, stream>>>(bsum, bsumx, offsets, NB, N);
    scan3_kernel<<<NB, 256, 0, stream>>>(counts, bsumx, offsets, cursor, dinv, N);
    fill_kernel<<<(E + 255) / 256, 256, 0, stream>>>(src, dst, dinv, cursor, ssrc, snorm, E);
    prepw_kernel<<<(204800 + 255) / 256, 256, 0, stream>>>(
        g1w, g2w, g3w, w3, Bt1f, Bt2f, Bt3, Bt0f);

    const int MB = (N + 127) / 128;     // 391 row-blocks (BM=128)
    const int MB8 = (MB + 7) & ~7;      // 392 (pad to 8 for swizzle)
    const int MB64 = (N + 63) / 64;     // 782 row-blocks (BM=64)

    // ---- MLP: x -> h2 fp16 (fused), h2 -> h3 fp16 (f16 MFMA, K=64) ----
    mlp12_kernel<<<NB, 256, 0, stream>>>(x, w1, b1, w2, b2, H2f, N);
    {   dim3 grid(1, MB);
        gemm_f16_kernel<128, 128, 4, 2, 2, 4, 4, 0><<<grid, 256, 0, stream>>>(
            H2f, Bt0f, b3, S128f, N, 64, 128);
    }

    // ---- GCN1: agg@128 -> f16 MFMA 128->256 swiz2 ----
    agg_f16_kernel<128><<<((size_t)N * 16 + 255) / 256, 256, 0, stream>>>(
        S128f, offsets, ssrc, snorm, dinv, A128f, N);
    gemm_f16_kernel<128, 128, 4, 2, 2, 4, 4, 2><<<2 * MB8, 256, 0, stream>>>(
        A128f, Bt1f, g1b, G1f, N, 128, 256);

    // ---- GCN2: agg@256 -> f16 MFMA 256->512 swiz4 ----
    agg_f16_kernel<256><<<((size_t)N * 32 + 255) / 256, 256, 0, stream>>>(
        G1f, offsets, ssrc, snorm, dinv, A256f, N);
    gemm_f16_kernel<128, 128, 4, 2, 2, 4, 4, 4><<<4 * MB8, 256, 0, stream>>>(
        A256f, Bt2f, g2b, A512f, N, 256, 512);

    // ---- GCN3: emulated MFMA 512->64 BM=64 (fp16 out) -> agg + softmax ----
    {   dim3 grid(1, MB64);
        gemm_emul_kernel<64, 64, 4, 4, 1, 1, 4><<<grid, 256, 0, stream>>>(
            A512f, Bt3, zbuf, N, 512, 64);
    }
    agg50_softmax_kernel<<<(N + 3) / 4, 256, 0, stream>>>(
        zbuf, offsets, ssrc, snorm, dinv, g3b, out, N);
}